// Round 1
// baseline (849.093 us; speedup 1.0000x reference)
//
#include <hip/hip_runtime.h>
#include <hip/hip_fp16.h>
#include <cstdint>
#include <cstddef>

typedef _Float16 f16x8 __attribute__((ext_vector_type(8)));
typedef _Float16 f16x4 __attribute__((ext_vector_type(4)));
typedef float    f32x4 __attribute__((ext_vector_type(4)));

#define GPTR(p) ((const __attribute__((address_space(1))) void*)(p))
#define SPTR(p) ((__attribute__((address_space(3))) void*)(p))

// ---------------------------------------------------------------------------
// Transpose + cast fp32 -> fp16 : W (R x C) row-major -> Wt (C x R) row-major
// ---------------------------------------------------------------------------
__global__ void transpose_cast_kernel(const float* __restrict__ W,
                                      _Float16* __restrict__ Wt,
                                      int R, int C) {
  __shared__ float tile[32][33];
  const int c  = blockIdx.x * 32 + threadIdx.x;
  const int r0 = blockIdx.y * 32;
  for (int i = threadIdx.y; i < 32; i += 8)
    tile[i][threadIdx.x] = W[(size_t)(r0 + i) * C + c];
  __syncthreads();
  const int out_c = r0 + threadIdx.x;   // new col = old row
  const int oc0   = blockIdx.x * 32;    // new row = old col
  for (int i = threadIdx.y; i < 32; i += 8)
    Wt[(size_t)(oc0 + i) * R + out_c] = (_Float16)tile[threadIdx.x][i];
}

// ---------------------------------------------------------------------------
// Flat cast fp32 -> fp16, float4 granularity
// ---------------------------------------------------------------------------
__global__ void cast_f32_f16_kernel(const float* __restrict__ src,
                                    _Float16* __restrict__ dst) {
  const size_t i = (size_t)blockIdx.x * 256 + threadIdx.x;
  const float4 v = ((const float4*)src)[i];
  f16x4 h;
  h[0] = (_Float16)v.x; h[1] = (_Float16)v.y;
  h[2] = (_Float16)v.z; h[3] = (_Float16)v.w;
  ((f16x4*)dst)[i] = h;
}

// ---------------------------------------------------------------------------
// 256x256 deep-pipelined GEMM: C(MxN) = A(MxK fp16) @ Bt(NxK fp16)^T + bias.
//   MODE 0: C = elu(acc + bias)           MODE 1: C = scale[row]*(acc + bias)
// Structure (learn_hip m201-class schedule, plain HIP):
//   - 512 threads = 8 waves (2M x 4N), per-wave output 128x64, 16x16x32 MFMA
//   - BK=32, TRIPLE-buffered LDS (6 x 16 KiB = 96 KiB): while computing tile t
//     (buf t%3), tile t+1 is resident, tile t+2 streams into buf (t+2)%3 via
//     global_load_lds (the buffer tile t-1 finished with).
//   - counted s_waitcnt vmcnt(4) + raw s_barrier ONCE per K-tile; vmcnt never
//     drains to 0 in the main loop -> no barrier-drain stall.
//   - LDS swizzle: row-pair p, sub=(row&1)*4+kc, 16B slot = p*8 + (sub^(p&7)).
//     ds_read_b128 fragment reads hit every slot-position exactly 2x (free),
//     global_load_lds dest stays linear (wave base + lane*16).
//   - s_setprio(1) around the 32-MFMA cluster; bijective XCD blockIdx swizzle.
// Buffers are DISTINCT named __shared__ arrays (switch on t%3) so LLVM alias
// analysis can tell the DMA target from the read buffer.
// ---------------------------------------------------------------------------
#define STAGE256(Asw, Bsw, kk) do {                                            \
    _Pragma("unroll")                                                          \
    for (int rep_ = 0; rep_ < 2; ++rep_)                                       \
      __builtin_amdgcn_global_load_lds(GPTR(asrc[rep_] + (kk)),                \
                                       SPTR((Asw) + ldst[rep_]), 16, 0, 0);    \
    _Pragma("unroll")                                                          \
    for (int rep_ = 0; rep_ < 2; ++rep_)                                       \
      __builtin_amdgcn_global_load_lds(GPTR(bsrc[rep_] + (kk)),                \
                                       SPTR((Bsw) + ldst[rep_]), 16, 0, 0);    \
  } while (0)

#define COMPUTE256(Asr, Bsr) do {                                              \
    f16x8 af[8], bf[4];                                                        \
    _Pragma("unroll")                                                          \
    for (int i_ = 0; i_ < 8; ++i_) {                                           \
      const int an_ = wm * 128 + i_ * 16 + r;                                  \
      const int ap_ = an_ >> 1;                                                \
      const int sl_ = ap_ * 8 + ((((an_ & 1) << 2) | quad) ^ (ap_ & 7));       \
      af[i_] = *(const f16x8*)((Asr) + sl_ * 8);                               \
    }                                                                          \
    _Pragma("unroll")                                                          \
    for (int j_ = 0; j_ < 4; ++j_) {                                           \
      const int bn_ = wn * 64 + j_ * 16 + r;                                   \
      const int bp_ = bn_ >> 1;                                                \
      const int sl_ = bp_ * 8 + ((((bn_ & 1) << 2) | quad) ^ (bp_ & 7));       \
      bf[j_] = *(const f16x8*)((Bsr) + sl_ * 8);                               \
    }                                                                          \
    __builtin_amdgcn_s_setprio(1);                                             \
    _Pragma("unroll")                                                          \
    for (int i_ = 0; i_ < 8; ++i_)                                             \
      _Pragma("unroll")                                                        \
      for (int j_ = 0; j_ < 4; ++j_)                                           \
        acc[i_][j_] = __builtin_amdgcn_mfma_f32_16x16x32_f16(af[i_], bf[j_],   \
                                                             acc[i_][j_],      \
                                                             0, 0, 0);         \
    __builtin_amdgcn_s_setprio(0);                                             \
  } while (0)

template <int MODE, bool OUTHALF>
__global__ __launch_bounds__(512, 2) void gemm256(
    const _Float16* __restrict__ A,
    const _Float16* __restrict__ Bt0, const _Float16* __restrict__ Bt1,
    const float* __restrict__ bias0, const float* __restrict__ bias1,
    int msplit, const float* __restrict__ scale,
    void* __restrict__ Cv, int K, int N) {
  // 6 distinct buffers: 256 rows x 32 halves = 16 KiB each, 96 KiB total.
  __shared__ __align__(16) _Float16 As0[8192], As1[8192], As2[8192];
  __shared__ __align__(16) _Float16 Bs0[8192], Bs1[8192], Bs2[8192];

  const int tid  = threadIdx.x;
  const int lane = tid & 63;
  const int wave = tid >> 6;
  const int quad = lane >> 4;
  const int r    = lane & 15;
  const int wm   = wave >> 2;   // 0..1  (M)
  const int wn   = wave & 3;    // 0..3  (N)

  // Bijective XCD-aware block swizzle (nwg is a multiple of 8 here).
  const int gx  = gridDim.x;
  const int nwg = gx * gridDim.y;
  int flat = blockIdx.y * gx + blockIdx.x;
  if ((nwg & 7) == 0) flat = (flat & 7) * (nwg >> 3) + (flat >> 3);
  const int m0 = (flat / gx) * 256;
  const int n0 = (flat % gx) * 256;

  const _Float16* Bt  = (m0 >= msplit) ? Bt1 : Bt0;
  const float*    bias = (m0 >= msplit) ? bias1 : bias0;

  // Per-lane staging sources (pre-swizzled) + wave-uniform LDS dest offsets.
  // Slot s in [0,1024): row-pair p=s>>3, sub=(s&7)^(p&7), row=2p+(sub>>2),
  // kc=sub&3. Each global_load_lds writes 512 contiguous 16B slots per rep.
  const _Float16* asrc[2];
  const _Float16* bsrc[2];
  int ldst[2];
#pragma unroll
  for (int rep = 0; rep < 2; ++rep) {
    const int s   = rep * 512 + tid;
    const int p   = s >> 3;
    const int sub = (s & 7) ^ (p & 7);
    const int row = p * 2 + (sub >> 2);
    const int kc  = sub & 3;
    asrc[rep] = A  + (size_t)(m0 + row) * K + kc * 8;
    bsrc[rep] = Bt + (size_t)(n0 + row) * K + kc * 8;
    ldst[rep] = (rep * 512 + wave * 64) * 8;   // halves (wave-uniform)
  }

  f32x4 acc[8][4] = {};
  const int NT = K >> 5;   // K/32 (>= 2 for all uses here)

  // Prologue: tiles 0 and 1 in flight (8 loads/thread).
  STAGE256(As0, Bs0, 0);
  STAGE256(As1, Bs1, 32);

  for (int t = 0; t < NT; ++t) {
    // Own tile-t loads are everything but the 4 newest (tile t+1's).
    if (t + 1 < NT) asm volatile("s_waitcnt vmcnt(4)" ::: "memory");
    else            asm volatile("s_waitcnt vmcnt(0)" ::: "memory");
    __builtin_amdgcn_s_barrier();           // all threads' tile-t DMA landed
    asm volatile("" ::: "memory");
    const int k2 = (t + 2) << 5;
    switch (t % 3) {
      case 0: if (t + 2 < NT) STAGE256(As2, Bs2, k2); COMPUTE256(As0, Bs0); break;
      case 1: if (t + 2 < NT) STAGE256(As0, Bs0, k2); COMPUTE256(As1, Bs1); break;
      default:if (t + 2 < NT) STAGE256(As1, Bs1, k2); COMPUTE256(As2, Bs2); break;
    }
  }

  // Epilogue: C/D layout col = lane&15, row = quad*4 + reg.
  float*    Cf = (float*)Cv;
  _Float16* Ch = (_Float16*)Cv;
#pragma unroll
  for (int i = 0; i < 8; ++i) {
    const int row0 = m0 + wm * 128 + i * 16 + quad * 4;
#pragma unroll
    for (int j = 0; j < 4; ++j) {
      const int col = n0 + wn * 64 + j * 16 + r;
      const float b = bias[col];
#pragma unroll
      for (int reg = 0; reg < 4; ++reg) {
        const int row = row0 + reg;
        float v = acc[i][j][reg] + b;
        if (MODE == 0) v = v > 0.f ? v : (expf(v) - 1.f);  // ELU (no +1)
        else           v = v * scale[row];
        if (OUTHALF) Ch[(size_t)row * N + col] = (_Float16)v;
        else         Cf[(size_t)row * N + col] = v;
      }
    }
  }
}

#undef STAGE256
#undef COMPUTE256

// ---------------------------------------------------------------------------
// Legacy 128x128 GEMM kept for the small-workspace fallback path.
// ---------------------------------------------------------------------------
template <int MODE, bool AHALF, bool OUTHALF>
__global__ __launch_bounds__(256) void gemm2(
    const void* __restrict__ Av,
    const _Float16* __restrict__ Bt0, const _Float16* __restrict__ Bt1,
    const float* __restrict__ bias0, const float* __restrict__ bias1,
    int msplit, const float* __restrict__ scale,
    void* __restrict__ Cv, int K, int N) {
  constexpr int BK = 64;
  __shared__ __align__(16) _Float16 As[128 * BK];
  __shared__ __align__(16) _Float16 Bs[128 * BK];

  const int tid  = threadIdx.x;
  const int lane = tid & 63;
  const int wave = tid >> 6;
  const int quad = lane >> 4;
  const int r    = lane & 15;
  const int wm   = wave >> 1;
  const int wn   = wave & 1;
  const int m0   = blockIdx.y * 128;
  const int n0   = blockIdx.x * 128;

  const _Float16* Bt  = (m0 >= msplit) ? Bt1 : Bt0;
  const float* bias   = (m0 >= msplit) ? bias1 : bias0;

  size_t aoff[4], boff[4];
  int slot[4];
#pragma unroll
  for (int t = 0; t < 4; ++t) {
    const int s  = wave * 256 + t * 64 + lane;
    const int n  = s >> 3;
    const int kc = (s & 7) ^ (n & 7);
    aoff[t] = (size_t)(m0 + n) * K + kc * 8;
    boff[t] = (size_t)(n0 + n) * K + kc * 8;
    slot[t] = s;
  }

  f32x4 acc[4][4] = {};
  const _Float16* Ah = (const _Float16*)Av;
  const float*    Af = (const float*)Av;

  for (int k0 = 0; k0 < K; k0 += BK) {
    __syncthreads();
    if (AHALF) {
#pragma unroll
      for (int t = 0; t < 4; ++t)
        __builtin_amdgcn_global_load_lds(GPTR(Ah + aoff[t] + k0),
                                         SPTR(As + (wave * 256 + t * 64) * 8),
                                         16, 0, 0);
    } else {
#pragma unroll
      for (int t = 0; t < 4; ++t) {
        const float* ap = Af + aoff[t] + k0;
        const float4 v0 = *(const float4*)ap;
        const float4 v1 = *(const float4*)(ap + 4);
        f16x8 h;
        h[0] = (_Float16)v0.x; h[1] = (_Float16)v0.y;
        h[2] = (_Float16)v0.z; h[3] = (_Float16)v0.w;
        h[4] = (_Float16)v1.x; h[5] = (_Float16)v1.y;
        h[6] = (_Float16)v1.z; h[7] = (_Float16)v1.w;
        *(f16x8*)(As + (size_t)slot[t] * 8) = h;
      }
    }
#pragma unroll
    for (int t = 0; t < 4; ++t)
      __builtin_amdgcn_global_load_lds(GPTR(Bt + boff[t] + k0),
                                       SPTR(Bs + (wave * 256 + t * 64) * 8),
                                       16, 0, 0);
    __syncthreads();

#pragma unroll
    for (int ki = 0; ki < 2; ++ki) {
      f16x8 af[4], bf[4];
#pragma unroll
      for (int i = 0; i < 4; ++i) {
        const int an = wm * 64 + i * 16 + r;
        af[i] = *(const f16x8*)(As + (an * 8 + ((ki * 4 + quad) ^ (an & 7))) * 8);
      }
#pragma unroll
      for (int j = 0; j < 4; ++j) {
        const int bn = wn * 64 + j * 16 + r;
        bf[j] = *(const f16x8*)(Bs + (bn * 8 + ((ki * 4 + quad) ^ (bn & 7))) * 8);
      }
#pragma unroll
      for (int i = 0; i < 4; ++i)
#pragma unroll
        for (int j = 0; j < 4; ++j)
          acc[i][j] = __builtin_amdgcn_mfma_f32_16x16x32_f16(af[i], bf[j],
                                                             acc[i][j], 0, 0, 0);
    }
  }

  float*    Cf = (float*)Cv;
  _Float16* Ch = (_Float16*)Cv;
#pragma unroll
  for (int i = 0; i < 4; ++i) {
#pragma unroll
    for (int j = 0; j < 4; ++j) {
      const int col = n0 + wn * 64 + j * 16 + r;
      const float b = bias[col];
#pragma unroll
      for (int reg = 0; reg < 4; ++reg) {
        const int row = m0 + wm * 64 + i * 16 + quad * 4 + reg;
        float v = acc[i][j][reg] + b;
        if (MODE == 0) v = v > 0.f ? v : (expf(v) - 1.f);
        else           v = v * scale[row];
        if (OUTHALF) Ch[(size_t)row * N + col] = (_Float16)v;
        else         Cf[(size_t)row * N + col] = v;
      }
    }
  }
}

// ---------------------------------------------------------------------------
// scale[b] = (Qf[b].Kf[b]) / (sum(Qf[b]) * sum(Kf[b]) + eps), F = 1024.
// ---------------------------------------------------------------------------
template <bool HALF>
__global__ void reduce_scale2(const void* __restrict__ Qf,
                              const void* __restrict__ Kf,
                              float* __restrict__ scale) {
  const int b = blockIdx.x;
  const int t = threadIdx.x;
  float q[4], k[4];
  if (HALF) {
    const f16x4 qh = ((const f16x4*)((const _Float16*)Qf + (size_t)b * 1024))[t];
    const f16x4 kh = ((const f16x4*)((const _Float16*)Kf + (size_t)b * 1024))[t];
#pragma unroll
    for (int i = 0; i < 4; ++i) { q[i] = (float)qh[i]; k[i] = (float)kh[i]; }
  } else {
    const float4 qv = ((const float4*)((const float*)Qf + (size_t)b * 1024))[t];
    const float4 kv = ((const float4*)((const float*)Kf + (size_t)b * 1024))[t];
    q[0] = qv.x; q[1] = qv.y; q[2] = qv.z; q[3] = qv.w;
    k[0] = kv.x; k[1] = kv.y; k[2] = kv.z; k[3] = kv.w;
  }
  float qk = q[0] * k[0] + q[1] * k[1] + q[2] * k[2] + q[3] * k[3];
  float sq = q[0] + q[1] + q[2] + q[3];
  float sk = k[0] + k[1] + k[2] + k[3];
#pragma unroll
  for (int off = 32; off > 0; off >>= 1) {
    qk += __shfl_down(qk, off, 64);
    sq += __shfl_down(sq, off, 64);
    sk += __shfl_down(sk, off, 64);
  }
  __shared__ float buf[3][4];
  const int lane = t & 63, wv = t >> 6;
  if (lane == 0) { buf[0][wv] = qk; buf[1][wv] = sq; buf[2][wv] = sk; }
  __syncthreads();
  if (t == 0) {
    const float QK = buf[0][0] + buf[0][1] + buf[0][2] + buf[0][3];
    const float SQ = buf[1][0] + buf[1][1] + buf[1][2] + buf[1][3];
    const float SK = buf[2][0] + buf[2][1] + buf[2][2] + buf[2][3];
    scale[b] = QK / (SQ * SK + 1e-6f);
  }
}

// ---------------------------------------------------------------------------
extern "C" void kernel_launch(void* const* d_in, const int* in_sizes, int n_in,
                              void* d_out, int out_size, void* d_ws,
                              size_t ws_size, hipStream_t stream) {
  const float* Q  = (const float*)d_in[0];
  const float* K_ = (const float*)d_in[1];
  const float* V  = (const float*)d_in[2];
  const float* Wq = (const float*)d_in[3];
  const float* bq = (const float*)d_in[4];
  const float* Wk = (const float*)d_in[5];
  const float* bk = (const float*)d_in[6];
  const float* Wv = (const float*)d_in[7];
  const float* bv = (const float*)d_in[8];
  float* out = (float*)d_out;

  const int B = 8192, D = 2048, F = 1024;
  const size_t MiB = 1u << 20;
  char* ws = (char*)d_ws;

  // Fast path ws layout:
  //   [0, 8M):    WqT(4M)+WkT(4M); later WvT(8M) overwrites (after feat GEMM)
  //   [8M, 40M):  QfH(16M)+KfH(16M) contiguous; later Vh(32M) overwrites
  //   [40M, +32K): scale
  const size_t NEED_FAST = 40 * MiB + 64 * 1024;

  if (ws_size >= NEED_FAST) {
    _Float16* WqT = (_Float16*)ws;
    _Float16* WkT = (_Float16*)(ws + 4 * MiB);
    _Float16* WvT = (_Float16*)ws;             // reuses weight region
    _Float16* QfH = (_Float16*)(ws + 8 * MiB);
    _Float16* KfH = (_Float16*)(ws + 24 * MiB);
    _Float16* Vh  = (_Float16*)(ws + 8 * MiB); // reuses feature region
    float* scale  = (float*)(ws + 40 * MiB);
    _Float16* Qh = (_Float16*)d_out;                  // d_out as fp16 scratch
    _Float16* Kh = (_Float16*)d_out + (size_t)B * D;  // adjacent -> stacked M

    dim3 tb(32, 8);
    transpose_cast_kernel<<<dim3(F / 32, D / 32), tb, 0, stream>>>(Wq, WqT, D, F);
    transpose_cast_kernel<<<dim3(F / 32, D / 32), tb, 0, stream>>>(Wk, WkT, D, F);
    const int castBlocks = (B * D / 4) / 256;  // 16384
    cast_f32_f16_kernel<<<castBlocks, 256, 0, stream>>>(Q,  Qh);
    cast_f32_f16_kernel<<<castBlocks, 256, 0, stream>>>(K_, Kh);

    // Stacked feature GEMM: M = 16384 ([Qh;Kh]), split at 8192 selects
    // Wq/bq vs Wk/bk. 4x64 = 256 blocks = 1/CU, 512 thr, 96 KiB LDS.
    gemm256<0, true><<<dim3(F / 256, (2 * B) / 256), 512, 0, stream>>>(
        Qh, WqT, WkT, bq, bk, B, nullptr, QfH, D, F);
    reduce_scale2<true><<<B, 256, 0, stream>>>(QfH, KfH, scale);

    cast_f32_f16_kernel<<<castBlocks, 256, 0, stream>>>(V, Vh);
    transpose_cast_kernel<<<dim3(D / 32, D / 32), tb, 0, stream>>>(Wv, WvT, D, D);
    gemm256<1, false><<<dim3(D / 256, B / 256), 512, 0, stream>>>(
        Vh, WvT, WvT, bv, bv, 1 << 30, scale, out, D, D);
  } else {
    // Fallback: fp32 A staging in-kernel, Qf/Kf fp32 in d_out.
    _Float16* WqT = (_Float16*)ws;
    _Float16* WkT = (_Float16*)(ws + 4 * MiB);
    _Float16* WvT = (_Float16*)(ws + 8 * MiB);
    float* scale  = (float*)(ws + 16 * MiB);
    float* Qf = out;
    float* Kf = out + (size_t)B * F;

    dim3 tb(32, 8);
    transpose_cast_kernel<<<dim3(F / 32, D / 32), tb, 0, stream>>>(Wq, WqT, D, F);
    transpose_cast_kernel<<<dim3(F / 32, D / 32), tb, 0, stream>>>(Wk, WkT, D, F);
    transpose_cast_kernel<<<dim3(D / 32, D / 32), tb, 0, stream>>>(Wv, WvT, D, D);

    gemm2<0, false, false><<<dim3(F / 128, B / 128), 256, 0, stream>>>(
        Q, WqT, WqT, bq, bq, 1 << 30, nullptr, Qf, D, F);
    gemm2<0, false, false><<<dim3(F / 128, B / 128), 256, 0, stream>>>(
        K_, WkT, WkT, bk, bk, 1 << 30, nullptr, Kf, D, F);
    reduce_scale2<false><<<B, 256, 0, stream>>>(Qf, Kf, scale);
    gemm2<1, false, false><<<dim3(D / 128, B / 128), 256, 0, stream>>>(
        V, WvT, WvT, bv, bv, 1 << 30, scale, out, D, D);
  }
}

// Round 2
// 535.385 us; speedup vs baseline: 1.5859x; 1.5859x over previous
//
#include <hip/hip_runtime.h>
#include <hip/hip_fp16.h>
#include <cstdint>
#include <cstddef>

typedef _Float16 f16x8 __attribute__((ext_vector_type(8)));
typedef _Float16 f16x4 __attribute__((ext_vector_type(4)));
typedef float    f32x4 __attribute__((ext_vector_type(4)));

#define GPTR(p) ((const __attribute__((address_space(1))) void*)(p))
#define SPTR(p) ((__attribute__((address_space(3))) void*)(p))

// ---------------------------------------------------------------------------
// Transpose + cast fp32 -> fp16 : W (R x C) row-major -> Wt (C x R) row-major
// ---------------------------------------------------------------------------
__global__ void transpose_cast_kernel(const float* __restrict__ W,
                                      _Float16* __restrict__ Wt,
                                      int R, int C) {
  __shared__ float tile[32][33];
  const int c  = blockIdx.x * 32 + threadIdx.x;
  const int r0 = blockIdx.y * 32;
  for (int i = threadIdx.y; i < 32; i += 8)
    tile[i][threadIdx.x] = W[(size_t)(r0 + i) * C + c];
  __syncthreads();
  const int out_c = r0 + threadIdx.x;   // new col = old row
  const int oc0   = blockIdx.x * 32;    // new row = old col
  for (int i = threadIdx.y; i < 32; i += 8)
    Wt[(size_t)(oc0 + i) * R + out_c] = (_Float16)tile[threadIdx.x][i];
}

// ---------------------------------------------------------------------------
// Flat cast fp32 -> fp16, float4 granularity
// ---------------------------------------------------------------------------
__global__ void cast_f32_f16_kernel(const float* __restrict__ src,
                                    _Float16* __restrict__ dst) {
  const size_t i = (size_t)blockIdx.x * 256 + threadIdx.x;
  const float4 v = ((const float4*)src)[i];
  f16x4 h;
  h[0] = (_Float16)v.x; h[1] = (_Float16)v.y;
  h[2] = (_Float16)v.z; h[3] = (_Float16)v.w;
  ((f16x4*)dst)[i] = h;
}

// ---------------------------------------------------------------------------
// 256x256 pipelined GEMM, 16 waves: C(MxN) = A(MxK fp16) @ Bt(NxK fp16)^T + b.
//   MODE 0: C = elu(acc + bias)           MODE 1: C = scale[row]*(acc + bias)
// Round-2 revision after the 8-wave/acc[8][4] version spilled (WRITE_SIZE
// 32MB -> 254MB = scratch flush traffic; MfmaUtil 8.9%):
//   - 1024 thr = 16 waves (4M x 4N), per-wave output 64x64 -> acc[4][4] = 64
//     regs/lane, the footprint PROVEN spill-free at 88 VGPR in the 128x128
//     kernel. __launch_bounds__(1024,4) caps at 128 VGPR (4 waves/SIMD).
//   - BK=64, DOUBLE-buffered LDS (4 x 32 KiB = 128 KiB) -> 1 block/CU,
//     16 waves resident (50% occupancy vs 21% in both prior versions).
//   - depth-1 prefetch with counted s_waitcnt vmcnt(4): tile t+1's 4 DMA
//     loads stay in flight across the barrier; vmcnt never drains to 0 in
//     the main loop (the m97-structure's ~20% barrier-drain stall removed).
//   - loop unrolled x2 with statically named buffers (no switch / runtime
//     buffer index -> no pressure blow-up); NT = K/64 is even for K=2048.
//   - LDS swizzle identical to the proven one: row n, k-chunk kc (8 halves)
//     at 16B slot n*8 + (kc ^ (n&7)); 0 bank conflicts measured, and the
//     global_load_lds dest stays linear (wave base + lane*16).
//   - bijective XCD swizzle (both grids are 256 blocks, 256 % 8 == 0):
//     kept from round 1 -- it cut FETCH_SIZE 266MB -> 56MB.
// ---------------------------------------------------------------------------
#define STAGE16(Asw, Bsw, kk) do {                                             \
    _Pragma("unroll")                                                          \
    for (int rep_ = 0; rep_ < 2; ++rep_)                                       \
      __builtin_amdgcn_global_load_lds(GPTR(asrc[rep_] + (kk)),                \
                                       SPTR((Asw) + ldst[rep_]), 16, 0, 0);    \
    _Pragma("unroll")                                                          \
    for (int rep_ = 0; rep_ < 2; ++rep_)                                       \
      __builtin_amdgcn_global_load_lds(GPTR(bsrc[rep_] + (kk)),                \
                                       SPTR((Bsw) + ldst[rep_]), 16, 0, 0);    \
  } while (0)

#define COMPUTE16(Asr, Bsr) do {                                               \
    _Pragma("unroll")                                                          \
    for (int ki_ = 0; ki_ < 2; ++ki_) {                                        \
      f16x8 af[4], bf[4];                                                      \
      _Pragma("unroll")                                                        \
      for (int i_ = 0; i_ < 4; ++i_) {                                         \
        const int an_ = wm * 64 + i_ * 16 + r;                                 \
        af[i_] = *(const f16x8*)((Asr) +                                       \
                 (an_ * 8 + ((ki_ * 4 + quad) ^ (an_ & 7))) * 8);              \
      }                                                                        \
      _Pragma("unroll")                                                        \
      for (int j_ = 0; j_ < 4; ++j_) {                                         \
        const int bn_ = wn * 64 + j_ * 16 + r;                                 \
        bf[j_] = *(const f16x8*)((Bsr) +                                       \
                 (bn_ * 8 + ((ki_ * 4 + quad) ^ (bn_ & 7))) * 8);              \
      }                                                                        \
      __builtin_amdgcn_s_setprio(1);                                           \
      _Pragma("unroll")                                                        \
      for (int i_ = 0; i_ < 4; ++i_)                                           \
        _Pragma("unroll")                                                      \
        for (int j_ = 0; j_ < 4; ++j_)                                         \
          acc[i_][j_] = __builtin_amdgcn_mfma_f32_16x16x32_f16(af[i_], bf[j_], \
                                                               acc[i_][j_],    \
                                                               0, 0, 0);       \
      __builtin_amdgcn_s_setprio(0);                                           \
    }                                                                          \
  } while (0)

template <int MODE, bool OUTHALF>
__global__ __launch_bounds__(1024, 4) void gemm256(
    const _Float16* __restrict__ A,
    const _Float16* __restrict__ Bt0, const _Float16* __restrict__ Bt1,
    const float* __restrict__ bias0, const float* __restrict__ bias1,
    int msplit, const float* __restrict__ scale,
    void* __restrict__ Cv, int K, int N) {
  // 4 buffers: 256 rows x 64 halves = 32 KiB each, 128 KiB total.
  __shared__ __align__(16) _Float16 As0[256 * 64], Bs0[256 * 64];
  __shared__ __align__(16) _Float16 As1[256 * 64], Bs1[256 * 64];

  const int tid  = threadIdx.x;
  const int lane = tid & 63;
  const int wave = tid >> 6;    // 0..15
  const int quad = lane >> 4;
  const int r    = lane & 15;
  const int wm   = wave >> 2;   // 0..3  (M)
  const int wn   = wave & 3;    // 0..3  (N)

  // Bijective XCD-aware block swizzle (both grids: 256 blocks, %8 == 0).
  const int gx  = gridDim.x;
  const int nwg = gx * gridDim.y;
  int flat = blockIdx.y * gx + blockIdx.x;
  if ((nwg & 7) == 0) flat = (flat & 7) * (nwg >> 3) + (flat >> 3);
  const int m0 = (flat / gx) * 256;
  const int n0 = (flat % gx) * 256;

  const _Float16* Bt   = (m0 >= msplit) ? Bt1 : Bt0;
  const float*    bias = (m0 >= msplit) ? bias1 : bias0;

  // Per-lane staging sources (pre-swizzled) + wave-uniform LDS dest offsets.
  // Chunk s in [0,2048): row n = s>>3, k-chunk kc = (s&7) ^ (n&7).
  const _Float16* asrc[2];
  const _Float16* bsrc[2];
  int ldst[2];
#pragma unroll
  for (int rep = 0; rep < 2; ++rep) {
    const int s  = rep * 1024 + tid;
    const int n  = s >> 3;
    const int kc = (s & 7) ^ (n & 7);
    asrc[rep] = A  + (size_t)(m0 + n) * K + kc * 8;
    bsrc[rep] = Bt + (size_t)(n0 + n) * K + kc * 8;
    ldst[rep] = (rep * 1024 + wave * 64) * 8;   // halves (wave-uniform base)
  }

  f32x4 acc[4][4] = {};
  const int NT = K >> 6;   // K/64; even for all uses here (K = 2048)

  STAGE16(As0, Bs0, 0);
  for (int t = 0; t < NT; t += 2) {
    // --- even tile t (in As0/Bs0); stage t+1 into As1/Bs1 ---
    STAGE16(As1, Bs1, (t + 1) << 6);
    asm volatile("s_waitcnt vmcnt(4)" ::: "memory");   // tile t landed
    __builtin_amdgcn_s_barrier();
    asm volatile("" ::: "memory");
    COMPUTE16(As0, Bs0);
    asm volatile("" ::: "memory");
    __builtin_amdgcn_s_barrier();                      // readers done w/ As0
    // --- odd tile t+1 (in As1/Bs1); stage t+2 into As0/Bs0 ---
    if (t + 2 < NT) {
      STAGE16(As0, Bs0, (t + 2) << 6);
      asm volatile("s_waitcnt vmcnt(4)" ::: "memory"); // tile t+1 landed
    } else {
      asm volatile("s_waitcnt vmcnt(0)" ::: "memory");
    }
    __builtin_amdgcn_s_barrier();
    asm volatile("" ::: "memory");
    COMPUTE16(As1, Bs1);
    asm volatile("" ::: "memory");
    __builtin_amdgcn_s_barrier();                      // readers done w/ As1
  }

  // Epilogue: C/D layout col = lane&15, row = quad*4 + reg.
  float*    Cf = (float*)Cv;
  _Float16* Ch = (_Float16*)Cv;
#pragma unroll
  for (int i = 0; i < 4; ++i) {
    const int row0 = m0 + wm * 64 + i * 16 + quad * 4;
#pragma unroll
    for (int j = 0; j < 4; ++j) {
      const int col = n0 + wn * 64 + j * 16 + r;
      const float b = bias[col];
#pragma unroll
      for (int reg = 0; reg < 4; ++reg) {
        const int row = row0 + reg;
        float v = acc[i][j][reg] + b;
        if (MODE == 0) v = v > 0.f ? v : (expf(v) - 1.f);  // ELU (no +1)
        else           v = v * scale[row];
        if (OUTHALF) Ch[(size_t)row * N + col] = (_Float16)v;
        else         Cf[(size_t)row * N + col] = v;
      }
    }
  }
}

#undef STAGE16
#undef COMPUTE16

// ---------------------------------------------------------------------------
// Legacy 128x128 GEMM kept for the small-workspace fallback path.
// ---------------------------------------------------------------------------
template <int MODE, bool AHALF, bool OUTHALF>
__global__ __launch_bounds__(256) void gemm2(
    const void* __restrict__ Av,
    const _Float16* __restrict__ Bt0, const _Float16* __restrict__ Bt1,
    const float* __restrict__ bias0, const float* __restrict__ bias1,
    int msplit, const float* __restrict__ scale,
    void* __restrict__ Cv, int K, int N) {
  constexpr int BK = 64;
  __shared__ __align__(16) _Float16 As[128 * BK];
  __shared__ __align__(16) _Float16 Bs[128 * BK];

  const int tid  = threadIdx.x;
  const int lane = tid & 63;
  const int wave = tid >> 6;
  const int quad = lane >> 4;
  const int r    = lane & 15;
  const int wm   = wave >> 1;
  const int wn   = wave & 1;
  const int m0   = blockIdx.y * 128;
  const int n0   = blockIdx.x * 128;

  const _Float16* Bt  = (m0 >= msplit) ? Bt1 : Bt0;
  const float* bias   = (m0 >= msplit) ? bias1 : bias0;

  size_t aoff[4], boff[4];
  int slot[4];
#pragma unroll
  for (int t = 0; t < 4; ++t) {
    const int s  = wave * 256 + t * 64 + lane;
    const int n  = s >> 3;
    const int kc = (s & 7) ^ (n & 7);
    aoff[t] = (size_t)(m0 + n) * K + kc * 8;
    boff[t] = (size_t)(n0 + n) * K + kc * 8;
    slot[t] = s;
  }

  f32x4 acc[4][4] = {};
  const _Float16* Ah = (const _Float16*)Av;
  const float*    Af = (const float*)Av;

  for (int k0 = 0; k0 < K; k0 += BK) {
    __syncthreads();
    if (AHALF) {
#pragma unroll
      for (int t = 0; t < 4; ++t)
        __builtin_amdgcn_global_load_lds(GPTR(Ah + aoff[t] + k0),
                                         SPTR(As + (wave * 256 + t * 64) * 8),
                                         16, 0, 0);
    } else {
#pragma unroll
      for (int t = 0; t < 4; ++t) {
        const float* ap = Af + aoff[t] + k0;
        const float4 v0 = *(const float4*)ap;
        const float4 v1 = *(const float4*)(ap + 4);
        f16x8 h;
        h[0] = (_Float16)v0.x; h[1] = (_Float16)v0.y;
        h[2] = (_Float16)v0.z; h[3] = (_Float16)v0.w;
        h[4] = (_Float16)v1.x; h[5] = (_Float16)v1.y;
        h[6] = (_Float16)v1.z; h[7] = (_Float16)v1.w;
        *(f16x8*)(As + (size_t)slot[t] * 8) = h;
      }
    }
#pragma unroll
    for (int t = 0; t < 4; ++t)
      __builtin_amdgcn_global_load_lds(GPTR(Bt + boff[t] + k0),
                                       SPTR(Bs + (wave * 256 + t * 64) * 8),
                                       16, 0, 0);
    __syncthreads();

#pragma unroll
    for (int ki = 0; ki < 2; ++ki) {
      f16x8 af[4], bf[4];
#pragma unroll
      for (int i = 0; i < 4; ++i) {
        const int an = wm * 64 + i * 16 + r;
        af[i] = *(const f16x8*)(As + (an * 8 + ((ki * 4 + quad) ^ (an & 7))) * 8);
      }
#pragma unroll
      for (int j = 0; j < 4; ++j) {
        const int bn = wn * 64 + j * 16 + r;
        bf[j] = *(const f16x8*)(Bs + (bn * 8 + ((ki * 4 + quad) ^ (bn & 7))) * 8);
      }
#pragma unroll
      for (int i = 0; i < 4; ++i)
#pragma unroll
        for (int j = 0; j < 4; ++j)
          acc[i][j] = __builtin_amdgcn_mfma_f32_16x16x32_f16(af[i], bf[j],
                                                             acc[i][j], 0, 0, 0);
    }
  }

  float*    Cf = (float*)Cv;
  _Float16* Ch = (_Float16*)Cv;
#pragma unroll
  for (int i = 0; i < 4; ++i) {
#pragma unroll
    for (int j = 0; j < 4; ++j) {
      const int col = n0 + wn * 64 + j * 16 + r;
      const float b = bias[col];
#pragma unroll
      for (int reg = 0; reg < 4; ++reg) {
        const int row = m0 + wm * 64 + i * 16 + quad * 4 + reg;
        float v = acc[i][j][reg] + b;
        if (MODE == 0) v = v > 0.f ? v : (expf(v) - 1.f);
        else           v = v * scale[row];
        if (OUTHALF) Ch[(size_t)row * N + col] = (_Float16)v;
        else         Cf[(size_t)row * N + col] = v;
      }
    }
  }
}

// ---------------------------------------------------------------------------
// scale[b] = (Qf[b].Kf[b]) / (sum(Qf[b]) * sum(Kf[b]) + eps), F = 1024.
// ---------------------------------------------------------------------------
template <bool HALF>
__global__ void reduce_scale2(const void* __restrict__ Qf,
                              const void* __restrict__ Kf,
                              float* __restrict__ scale) {
  const int b = blockIdx.x;
  const int t = threadIdx.x;
  float q[4], k[4];
  if (HALF) {
    const f16x4 qh = ((const f16x4*)((const _Float16*)Qf + (size_t)b * 1024))[t];
    const f16x4 kh = ((const f16x4*)((const _Float16*)Kf + (size_t)b * 1024))[t];
#pragma unroll
    for (int i = 0; i < 4; ++i) { q[i] = (float)qh[i]; k[i] = (float)kh[i]; }
  } else {
    const float4 qv = ((const float4*)((const float*)Qf + (size_t)b * 1024))[t];
    const float4 kv = ((const float4*)((const float*)Kf + (size_t)b * 1024))[t];
    q[0] = qv.x; q[1] = qv.y; q[2] = qv.z; q[3] = qv.w;
    k[0] = kv.x; k[1] = kv.y; k[2] = kv.z; k[3] = kv.w;
  }
  float qk = q[0] * k[0] + q[1] * k[1] + q[2] * k[2] + q[3] * k[3];
  float sq = q[0] + q[1] + q[2] + q[3];
  float sk = k[0] + k[1] + k[2] + k[3];
#pragma unroll
  for (int off = 32; off > 0; off >>= 1) {
    qk += __shfl_down(qk, off, 64);
    sq += __shfl_down(sq, off, 64);
    sk += __shfl_down(sk, off, 64);
  }
  __shared__ float buf[3][4];
  const int lane = t & 63, wv = t >> 6;
  if (lane == 0) { buf[0][wv] = qk; buf[1][wv] = sq; buf[2][wv] = sk; }
  __syncthreads();
  if (t == 0) {
    const float QK = buf[0][0] + buf[0][1] + buf[0][2] + buf[0][3];
    const float SQ = buf[1][0] + buf[1][1] + buf[1][2] + buf[1][3];
    const float SK = buf[2][0] + buf[2][1] + buf[2][2] + buf[2][3];
    scale[b] = QK / (SQ * SK + 1e-6f);
  }
}

// ---------------------------------------------------------------------------
extern "C" void kernel_launch(void* const* d_in, const int* in_sizes, int n_in,
                              void* d_out, int out_size, void* d_ws,
                              size_t ws_size, hipStream_t stream) {
  const float* Q  = (const float*)d_in[0];
  const float* K_ = (const float*)d_in[1];
  const float* V  = (const float*)d_in[2];
  const float* Wq = (const float*)d_in[3];
  const float* bq = (const float*)d_in[4];
  const float* Wk = (const float*)d_in[5];
  const float* bk = (const float*)d_in[6];
  const float* Wv = (const float*)d_in[7];
  const float* bv = (const float*)d_in[8];
  float* out = (float*)d_out;

  const int B = 8192, D = 2048, F = 1024;
  const size_t MiB = 1u << 20;
  char* ws = (char*)d_ws;

  // Fast path ws layout:
  //   [0, 8M):    WqT(4M)+WkT(4M); later WvT(8M) overwrites (after feat GEMM)
  //   [8M, 40M):  QfH(16M)+KfH(16M) contiguous; later Vh(32M) overwrites
  //   [40M, +32K): scale
  const size_t NEED_FAST = 40 * MiB + 64 * 1024;

  if (ws_size >= NEED_FAST) {
    _Float16* WqT = (_Float16*)ws;
    _Float16* WkT = (_Float16*)(ws + 4 * MiB);
    _Float16* WvT = (_Float16*)ws;             // reuses weight region
    _Float16* QfH = (_Float16*)(ws + 8 * MiB);
    _Float16* KfH = (_Float16*)(ws + 24 * MiB);
    _Float16* Vh  = (_Float16*)(ws + 8 * MiB); // reuses feature region
    float* scale  = (float*)(ws + 40 * MiB);
    _Float16* Qh = (_Float16*)d_out;                  // d_out as fp16 scratch
    _Float16* Kh = (_Float16*)d_out + (size_t)B * D;  // adjacent -> stacked M

    dim3 tb(32, 8);
    transpose_cast_kernel<<<dim3(F / 32, D / 32), tb, 0, stream>>>(Wq, WqT, D, F);
    transpose_cast_kernel<<<dim3(F / 32, D / 32), tb, 0, stream>>>(Wk, WkT, D, F);
    const int castBlocks = (B * D / 4) / 256;  // 16384
    cast_f32_f16_kernel<<<castBlocks, 256, 0, stream>>>(Q,  Qh);
    cast_f32_f16_kernel<<<castBlocks, 256, 0, stream>>>(K_, Kh);

    // Stacked feature GEMM: M = 16384 ([Qh;Kh]), split at 8192 selects
    // Wq/bq vs Wk/bk. Grid 4x64 = 256 blocks = 1/CU, 1024 thr, 128 KiB LDS.
    gemm256<0, true><<<dim3(F / 256, (2 * B) / 256), 1024, 0, stream>>>(
        Qh, WqT, WkT, bq, bk, B, nullptr, QfH, D, F);
    reduce_scale2<true><<<B, 256, 0, stream>>>(QfH, KfH, scale);

    cast_f32_f16_kernel<<<castBlocks, 256, 0, stream>>>(V, Vh);
    transpose_cast_kernel<<<dim3(D / 32, D / 32), tb, 0, stream>>>(Wv, WvT, D, D);
    gemm256<1, false><<<dim3(D / 256, B / 256), 1024, 0, stream>>>(
        Vh, WvT, WvT, bv, bv, 1 << 30, scale, out, D, D);
  } else {
    // Fallback: fp32 A staging in-kernel, Qf/Kf fp32 in d_out.
    _Float16* WqT = (_Float16*)ws;
    _Float16* WkT = (_Float16*)(ws + 4 * MiB);
    _Float16* WvT = (_Float16*)(ws + 8 * MiB);
    float* scale  = (float*)(ws + 16 * MiB);
    float* Qf = out;
    float* Kf = out + (size_t)B * F;

    dim3 tb(32, 8);
    transpose_cast_kernel<<<dim3(F / 32, D / 32), tb, 0, stream>>>(Wq, WqT, D, F);
    transpose_cast_kernel<<<dim3(F / 32, D / 32), tb, 0, stream>>>(Wk, WkT, D, F);
    transpose_cast_kernel<<<dim3(D / 32, D / 32), tb, 0, stream>>>(Wv, WvT, D, D);

    gemm2<0, false, false><<<dim3(F / 128, B / 128), 256, 0, stream>>>(
        Q, WqT, WqT, bq, bq, 1 << 30, nullptr, Qf, D, F);
    gemm2<0, false, false><<<dim3(F / 128, B / 128), 256, 0, stream>>>(
        K_, WkT, WkT, bk, bk, 1 << 30, nullptr, Kf, D, F);
    reduce_scale2<false><<<B, 256, 0, stream>>>(Qf, Kf, scale);
    gemm2<1, false, false><<<dim3(D / 128, B / 128), 256, 0, stream>>>(
        V, WvT, WvT, bv, bv, 1 << 30, scale, out, D, D);
  }
}

// Round 3
// 441.056 us; speedup vs baseline: 1.9251x; 1.2139x over previous
//
#include <hip/hip_runtime.h>
#include <hip/hip_fp16.h>
#include <cstdint>
#include <cstddef>

typedef _Float16 f16x8 __attribute__((ext_vector_type(8)));
typedef _Float16 f16x4 __attribute__((ext_vector_type(4)));
typedef float    f32x4 __attribute__((ext_vector_type(4)));

#define GPTR(p) ((const __attribute__((address_space(1))) void*)(p))
#define SPTR(p) ((__attribute__((address_space(3))) void*)(p))

// ---------------------------------------------------------------------------
// Transpose + cast fp32 -> fp16 : W (R x C) row-major -> Wt (C x R) row-major
// ---------------------------------------------------------------------------
__global__ void transpose_cast_kernel(const float* __restrict__ W,
                                      _Float16* __restrict__ Wt,
                                      int R, int C) {
  __shared__ float tile[32][33];
  const int c  = blockIdx.x * 32 + threadIdx.x;
  const int r0 = blockIdx.y * 32;
  for (int i = threadIdx.y; i < 32; i += 8)
    tile[i][threadIdx.x] = W[(size_t)(r0 + i) * C + c];
  __syncthreads();
  const int out_c = r0 + threadIdx.x;   // new col = old row
  const int oc0   = blockIdx.x * 32;    // new row = old col
  for (int i = threadIdx.y; i < 32; i += 8)
    Wt[(size_t)(oc0 + i) * R + out_c] = (_Float16)tile[threadIdx.x][i];
}

// ---------------------------------------------------------------------------
// Flat cast fp32 -> fp16, float4 granularity
// ---------------------------------------------------------------------------
__global__ void cast_f32_f16_kernel(const float* __restrict__ src,
                                    _Float16* __restrict__ dst) {
  const size_t i = (size_t)blockIdx.x * 256 + threadIdx.x;
  const float4 v = ((const float4*)src)[i];
  f16x4 h;
  h[0] = (_Float16)v.x; h[1] = (_Float16)v.y;
  h[2] = (_Float16)v.z; h[3] = (_Float16)v.w;
  ((f16x4*)dst)[i] = h;
}

// ---------------------------------------------------------------------------
// 256x256 deep-pipelined GEMM (m201-class), 8 waves, BK=32, 3-tile prefetch.
//   C(MxN) = A(MxK fp16) @ Bt(NxK fp16)^T + bias
//   MODE 0: C = elu(acc + bias)           MODE 1: C = scale[row]*(acc + bias)
// Round-3 design (after round-2's depth-1 pipeline proved latency-bound:
// 12k cyc/tile vs 600 cyc of MFMA):
//   - 512 thr = 8 waves (2M x 4N), per-wave 128x64 -> acc[8][4] (128 VGPR,
//     fits the 256 cap of __launch_bounds__(512,2); straight-line body).
//   - LDS = ring of 8 half-tile slots PER OPERAND (half-tile = 128 rows x
//     BK=32 halves = 8 KiB = 1 load/thread). 2x64 KiB = 128 KiB = 4 K-tiles
//     resident -> staging runs 3 TILES ahead of compute.
//   - window t (2 phases): p0 stages (t+3) lo-halves, waits vmcnt(10)
//     (= tiles t+1,t+2 (8 loads) + t+3-lo (2) still in flight -> never
//     drains), barrier, 8 ds_read_b128, 16 MFMA; p1 stages (t+3) hi-halves,
//     barrier, 4 ds_read, 16 MFMA. Two barriers/phase bound wave drift so
//     a stage can never overwrite a slot a slower wave still reads
//     (stage slot is 3 tiles ahead; nearest reuse is separated by the
//     post-MFMA barrier of the previous window).
//   - pair-swizzle LDS layout (round-1's, measured 0 bank conflicts):
//     16B slot s holds (row lr, chunk c): p=s>>3, sub=(s&7)^(p&7),
//     lr=2p+(sub>>2), c=sub&3. Reads are 2-way bank aliased = free (m136).
//     global_load_lds dest stays linear (slot base + lane*16).
//   - bijective XCD swizzle (grids are 256 blocks) + s_setprio around MFMA.
// ---------------------------------------------------------------------------
#define STG8(kk, h, slotv) do {                                                \
    __builtin_amdgcn_global_load_lds(GPTR(aRow + (h) * hstep + (kk)),          \
        SPTR(Aring + (slotv) * 4096 + wave * 512), 16, 0, 0);                  \
    __builtin_amdgcn_global_load_lds(GPTR(bRow + (h) * hstep + (kk)),          \
        SPTR(Bring + (slotv) * 4096 + wave * 512), 16, 0, 0);                  \
  } while (0)

#define WINDOW8(t_, DOSTG, VCSTR) do {                                         \
    const int e_ = (2 * (t_)) & 7;                                             \
    if (DOSTG) STG8(((t_) + 3) * 32, 0, (e_ + 6) & 7);                         \
    asm volatile("s_waitcnt vmcnt(" VCSTR ")" ::: "memory");                   \
    __builtin_amdgcn_s_barrier();                                              \
    asm volatile("" ::: "memory");                                             \
    const _Float16* Ab_ = Aring + ((e_ + wm) & 7) * 4096;                      \
    const _Float16* Bb_ = Bring + ((e_ + (wn >> 1)) & 7) * 4096               \
                          + (wn & 1) * 2048;                                   \
    f16x8 bf_[4], af_[4];                                                      \
    _Pragma("unroll")                                                          \
    for (int j_ = 0; j_ < 4; ++j_)                                             \
      bf_[j_] = *(const f16x8*)(Bb_ + j_ * 512 + lane_c * 8);                  \
    _Pragma("unroll")                                                          \
    for (int i_ = 0; i_ < 4; ++i_)                                             \
      af_[i_] = *(const f16x8*)(Ab_ + i_ * 512 + lane_c * 8);                  \
    __builtin_amdgcn_s_setprio(1);                                             \
    _Pragma("unroll")                                                          \
    for (int i_ = 0; i_ < 4; ++i_)                                             \
      _Pragma("unroll")                                                        \
      for (int j_ = 0; j_ < 4; ++j_)                                           \
        acc[i_][j_] = __builtin_amdgcn_mfma_f32_16x16x32_f16(af_[i_], bf_[j_], \
                                                             acc[i_][j_],      \
                                                             0, 0, 0);         \
    __builtin_amdgcn_s_setprio(0);                                             \
    asm volatile("" ::: "memory");                                             \
    __builtin_amdgcn_s_barrier();                                              \
    if (DOSTG) STG8(((t_) + 3) * 32, 1, (e_ + 7) & 7);                         \
    __builtin_amdgcn_s_barrier();                                              \
    asm volatile("" ::: "memory");                                             \
    _Pragma("unroll")                                                          \
    for (int i_ = 0; i_ < 4; ++i_)                                             \
      af_[i_] = *(const f16x8*)(Ab_ + (i_ + 4) * 512 + lane_c * 8);            \
    __builtin_amdgcn_s_setprio(1);                                             \
    _Pragma("unroll")                                                          \
    for (int i_ = 0; i_ < 4; ++i_)                                             \
      _Pragma("unroll")                                                        \
      for (int j_ = 0; j_ < 4; ++j_)                                           \
        acc[i_ + 4][j_] = __builtin_amdgcn_mfma_f32_16x16x32_f16(af_[i_],      \
                                                                 bf_[j_],      \
                                                                 acc[i_ + 4][j_],\
                                                                 0, 0, 0);     \
    __builtin_amdgcn_s_setprio(0);                                             \
    asm volatile("" ::: "memory");                                             \
    __builtin_amdgcn_s_barrier();                                              \
  } while (0)

template <int MODE, bool OUTHALF>
__global__ __launch_bounds__(512, 2) void gemm8p(
    const _Float16* __restrict__ A,
    const _Float16* __restrict__ Bt0, const _Float16* __restrict__ Bt1,
    const float* __restrict__ bias0, const float* __restrict__ bias1,
    int msplit, const float* __restrict__ scale,
    void* __restrict__ Cv, int K, int N) {
  // 8 half-tile slots per operand, 8 KiB (4096 halves) each: 128 KiB total.
  __shared__ __align__(16) _Float16 Aring[8 * 4096];
  __shared__ __align__(16) _Float16 Bring[8 * 4096];

  const int tid  = threadIdx.x;
  const int lane = tid & 63;
  const int wave = tid >> 6;       // 0..7
  const int quad = lane >> 4;
  const int r    = lane & 15;
  const int wm   = wave >> 2;      // 0..1  (M half)
  const int wn   = wave & 3;       // 0..3  (N quarter)

  // Bijective XCD-aware block swizzle (both grids: 256 blocks, %8 == 0).
  const int gx  = gridDim.x;
  const int nwg = gx * gridDim.y;
  int flat = blockIdx.y * gx + blockIdx.x;
  if ((nwg & 7) == 0) flat = (flat & 7) * (nwg >> 3) + (flat >> 3);
  const int m0 = (flat / gx) * 256;
  const int n0 = (flat % gx) * 256;

  const _Float16* Bt   = (m0 >= msplit) ? Bt1 : Bt0;
  const float*    bias = (m0 >= msplit) ? bias1 : bias0;

  // Per-thread staging source (pair-swizzle): 16B slot s = tid.
  const int sp  = tid >> 3;
  const int sub = (tid & 7) ^ (sp & 7);
  const int lr  = sp * 2 + (sub >> 2);   // local row in the 128-row half
  const int sc  = sub & 3;               // k-chunk (8 halves)
  const _Float16* aRow = A  + (size_t)(m0 + lr) * K + sc * 8;
  const _Float16* bRow = Bt + (size_t)(n0 + lr) * K + sc * 8;
  const int hstep = 128 * K;             // elements: half 0 -> half 1

  // Per-lane read constant: frag (lr=i*16+r, c=quad) lives at 16B slot
  // i*64 + lane_c, lane_c = (r>>1)*8 + ((((r&1)<<2)|quad) ^ (r>>1)).
  const int lane_c = (r >> 1) * 8 + (((((r & 1) << 2) | quad)) ^ (r >> 1));

  f32x4 acc[8][4] = {};
  const int NT = K >> 5;   // K/32 = 64 here (>= 4 required)

  // Prologue: stage tiles 0,1,2 (12 loads/thread, in order).
#pragma unroll
  for (int tt = 0; tt < 3; ++tt) {
    STG8(tt * 32, 0, (2 * tt) & 7);
    STG8(tt * 32, 1, (2 * tt + 1) & 7);
  }

  for (int t = 0; t < NT - 3; ++t) WINDOW8(t, 1, "10");
  WINDOW8(NT - 3, 0, "8");
  WINDOW8(NT - 2, 0, "4");
  WINDOW8(NT - 1, 0, "0");

  // Epilogue: C/D layout col = lane&15, row = quad*4 + reg.
  float*    Cf = (float*)Cv;
  _Float16* Ch = (_Float16*)Cv;
#pragma unroll
  for (int i = 0; i < 8; ++i) {
    const int row0 = m0 + wm * 128 + i * 16 + quad * 4;
#pragma unroll
    for (int j = 0; j < 4; ++j) {
      const int col = n0 + wn * 64 + j * 16 + r;
      const float b = bias[col];
#pragma unroll
      for (int reg = 0; reg < 4; ++reg) {
        const int row = row0 + reg;
        float v = acc[i][j][reg] + b;
        if (MODE == 0) v = v > 0.f ? v : (expf(v) - 1.f);  // ELU (no +1)
        else           v = v * scale[row];
        if (OUTHALF) Ch[(size_t)row * N + col] = (_Float16)v;
        else         Cf[(size_t)row * N + col] = v;
      }
    }
  }
}

#undef STG8
#undef WINDOW8

// ---------------------------------------------------------------------------
// Legacy 128x128 GEMM kept for the small-workspace fallback path.
// ---------------------------------------------------------------------------
template <int MODE, bool AHALF, bool OUTHALF>
__global__ __launch_bounds__(256) void gemm2(
    const void* __restrict__ Av,
    const _Float16* __restrict__ Bt0, const _Float16* __restrict__ Bt1,
    const float* __restrict__ bias0, const float* __restrict__ bias1,
    int msplit, const float* __restrict__ scale,
    void* __restrict__ Cv, int K, int N) {
  constexpr int BK = 64;
  __shared__ __align__(16) _Float16 As[128 * BK];
  __shared__ __align__(16) _Float16 Bs[128 * BK];

  const int tid  = threadIdx.x;
  const int lane = tid & 63;
  const int wave = tid >> 6;
  const int quad = lane >> 4;
  const int r    = lane & 15;
  const int wm   = wave >> 1;
  const int wn   = wave & 1;
  const int m0   = blockIdx.y * 128;
  const int n0   = blockIdx.x * 128;

  const _Float16* Bt  = (m0 >= msplit) ? Bt1 : Bt0;
  const float* bias   = (m0 >= msplit) ? bias1 : bias0;

  size_t aoff[4], boff[4];
  int slot[4];
#pragma unroll
  for (int t = 0; t < 4; ++t) {
    const int s  = wave * 256 + t * 64 + lane;
    const int n  = s >> 3;
    const int kc = (s & 7) ^ (n & 7);
    aoff[t] = (size_t)(m0 + n) * K + kc * 8;
    boff[t] = (size_t)(n0 + n) * K + kc * 8;
    slot[t] = s;
  }

  f32x4 acc[4][4] = {};
  const _Float16* Ah = (const _Float16*)Av;
  const float*    Af = (const float*)Av;

  for (int k0 = 0; k0 < K; k0 += BK) {
    __syncthreads();
    if (AHALF) {
#pragma unroll
      for (int t = 0; t < 4; ++t)
        __builtin_amdgcn_global_load_lds(GPTR(Ah + aoff[t] + k0),
                                         SPTR(As + (wave * 256 + t * 64) * 8),
                                         16, 0, 0);
    } else {
#pragma unroll
      for (int t = 0; t < 4; ++t) {
        const float* ap = Af + aoff[t] + k0;
        const float4 v0 = *(const float4*)ap;
        const float4 v1 = *(const float4*)(ap + 4);
        f16x8 h;
        h[0] = (_Float16)v0.x; h[1] = (_Float16)v0.y;
        h[2] = (_Float16)v0.z; h[3] = (_Float16)v0.w;
        h[4] = (_Float16)v1.x; h[5] = (_Float16)v1.y;
        h[6] = (_Float16)v1.z; h[7] = (_Float16)v1.w;
        *(f16x8*)(As + (size_t)slot[t] * 8) = h;
      }
    }
#pragma unroll
    for (int t = 0; t < 4; ++t)
      __builtin_amdgcn_global_load_lds(GPTR(Bt + boff[t] + k0),
                                       SPTR(Bs + (wave * 256 + t * 64) * 8),
                                       16, 0, 0);
    __syncthreads();

#pragma unroll
    for (int ki = 0; ki < 2; ++ki) {
      f16x8 af[4], bf[4];
#pragma unroll
      for (int i = 0; i < 4; ++i) {
        const int an = wm * 64 + i * 16 + r;
        af[i] = *(const f16x8*)(As + (an * 8 + ((ki * 4 + quad) ^ (an & 7))) * 8);
      }
#pragma unroll
      for (int j = 0; j < 4; ++j) {
        const int bn = wn * 64 + j * 16 + r;
        bf[j] = *(const f16x8*)(Bs + (bn * 8 + ((ki * 4 + quad) ^ (bn & 7))) * 8);
      }
#pragma unroll
      for (int i = 0; i < 4; ++i)
#pragma unroll
        for (int j = 0; j < 4; ++j)
          acc[i][j] = __builtin_amdgcn_mfma_f32_16x16x32_f16(af[i], bf[j],
                                                             acc[i][j], 0, 0, 0);
    }
  }

  float*    Cf = (float*)Cv;
  _Float16* Ch = (_Float16*)Cv;
#pragma unroll
  for (int i = 0; i < 4; ++i) {
#pragma unroll
    for (int j = 0; j < 4; ++j) {
      const int col = n0 + wn * 64 + j * 16 + r;
      const float b = bias[col];
#pragma unroll
      for (int reg = 0; reg < 4; ++reg) {
        const int row = m0 + wm * 64 + i * 16 + quad * 4 + reg;
        float v = acc[i][j][reg] + b;
        if (MODE == 0) v = v > 0.f ? v : (expf(v) - 1.f);
        else           v = v * scale[row];
        if (OUTHALF) Ch[(size_t)row * N + col] = (_Float16)v;
        else         Cf[(size_t)row * N + col] = v;
      }
    }
  }
}

// ---------------------------------------------------------------------------
// scale[b] = (Qf[b].Kf[b]) / (sum(Qf[b]) * sum(Kf[b]) + eps), F = 1024.
// ---------------------------------------------------------------------------
template <bool HALF>
__global__ void reduce_scale2(const void* __restrict__ Qf,
                              const void* __restrict__ Kf,
                              float* __restrict__ scale) {
  const int b = blockIdx.x;
  const int t = threadIdx.x;
  float q[4], k[4];
  if (HALF) {
    const f16x4 qh = ((const f16x4*)((const _Float16*)Qf + (size_t)b * 1024))[t];
    const f16x4 kh = ((const f16x4*)((const _Float16*)Kf + (size_t)b * 1024))[t];
#pragma unroll
    for (int i = 0; i < 4; ++i) { q[i] = (float)qh[i]; k[i] = (float)kh[i]; }
  } else {
    const float4 qv = ((const float4*)((const float*)Qf + (size_t)b * 1024))[t];
    const float4 kv = ((const float4*)((const float*)Kf + (size_t)b * 1024))[t];
    q[0] = qv.x; q[1] = qv.y; q[2] = qv.z; q[3] = qv.w;
    k[0] = kv.x; k[1] = kv.y; k[2] = kv.z; k[3] = kv.w;
  }
  float qk = q[0] * k[0] + q[1] * k[1] + q[2] * k[2] + q[3] * k[3];
  float sq = q[0] + q[1] + q[2] + q[3];
  float sk = k[0] + k[1] + k[2] + k[3];
#pragma unroll
  for (int off = 32; off > 0; off >>= 1) {
    qk += __shfl_down(qk, off, 64);
    sq += __shfl_down(sq, off, 64);
    sk += __shfl_down(sk, off, 64);
  }
  __shared__ float buf[3][4];
  const int lane = t & 63, wv = t >> 6;
  if (lane == 0) { buf[0][wv] = qk; buf[1][wv] = sq; buf[2][wv] = sk; }
  __syncthreads();
  if (t == 0) {
    const float QK = buf[0][0] + buf[0][1] + buf[0][2] + buf[0][3];
    const float SQ = buf[1][0] + buf[1][1] + buf[1][2] + buf[1][3];
    const float SK = buf[2][0] + buf[2][1] + buf[2][2] + buf[2][3];
    scale[b] = QK / (SQ * SK + 1e-6f);
  }
}

// ---------------------------------------------------------------------------
extern "C" void kernel_launch(void* const* d_in, const int* in_sizes, int n_in,
                              void* d_out, int out_size, void* d_ws,
                              size_t ws_size, hipStream_t stream) {
  const float* Q  = (const float*)d_in[0];
  const float* K_ = (const float*)d_in[1];
  const float* V  = (const float*)d_in[2];
  const float* Wq = (const float*)d_in[3];
  const float* bq = (const float*)d_in[4];
  const float* Wk = (const float*)d_in[5];
  const float* bk = (const float*)d_in[6];
  const float* Wv = (const float*)d_in[7];
  const float* bv = (const float*)d_in[8];
  float* out = (float*)d_out;

  const int B = 8192, D = 2048, F = 1024;
  const size_t MiB = 1u << 20;
  char* ws = (char*)d_ws;

  // Fast path ws layout:
  //   [0, 8M):    WqT(4M)+WkT(4M); later WvT(8M) overwrites (after feat GEMM)
  //   [8M, 40M):  QfH(16M)+KfH(16M) contiguous; later Vh(32M) overwrites
  //   [40M, +32K): scale
  const size_t NEED_FAST = 40 * MiB + 64 * 1024;

  if (ws_size >= NEED_FAST) {
    _Float16* WqT = (_Float16*)ws;
    _Float16* WkT = (_Float16*)(ws + 4 * MiB);
    _Float16* WvT = (_Float16*)ws;             // reuses weight region
    _Float16* QfH = (_Float16*)(ws + 8 * MiB);
    _Float16* KfH = (_Float16*)(ws + 24 * MiB);
    _Float16* Vh  = (_Float16*)(ws + 8 * MiB); // reuses feature region
    float* scale  = (float*)(ws + 40 * MiB);
    _Float16* Qh = (_Float16*)d_out;                  // d_out as fp16 scratch
    _Float16* Kh = (_Float16*)d_out + (size_t)B * D;  // adjacent -> stacked M

    dim3 tb(32, 8);
    transpose_cast_kernel<<<dim3(F / 32, D / 32), tb, 0, stream>>>(Wq, WqT, D, F);
    transpose_cast_kernel<<<dim3(F / 32, D / 32), tb, 0, stream>>>(Wk, WkT, D, F);
    const int castBlocks = (B * D / 4) / 256;  // 16384
    cast_f32_f16_kernel<<<castBlocks, 256, 0, stream>>>(Q,  Qh);
    cast_f32_f16_kernel<<<castBlocks, 256, 0, stream>>>(K_, Kh);

    // Stacked feature GEMM: M = 16384 ([Qh;Kh]), split at 8192 selects
    // Wq/bq vs Wk/bk. Grid 4x64 = 256 blocks = 1/CU, 512 thr, 128 KiB LDS.
    gemm8p<0, true><<<dim3(F / 256, (2 * B) / 256), 512, 0, stream>>>(
        Qh, WqT, WkT, bq, bk, B, nullptr, QfH, D, F);
    reduce_scale2<true><<<B, 256, 0, stream>>>(QfH, KfH, scale);

    cast_f32_f16_kernel<<<castBlocks, 256, 0, stream>>>(V, Vh);
    transpose_cast_kernel<<<dim3(D / 32, D / 32), tb, 0, stream>>>(Wv, WvT, D, D);
    gemm8p<1, false><<<dim3(D / 256, B / 256), 512, 0, stream>>>(
        Vh, WvT, WvT, bv, bv, 1 << 30, scale, out, D, D);
  } else {
    // Fallback: fp32 A staging in-kernel, Qf/Kf fp32 in d_out.
    _Float16* WqT = (_Float16*)ws;
    _Float16* WkT = (_Float16*)(ws + 4 * MiB);
    _Float16* WvT = (_Float16*)(ws + 8 * MiB);
    float* scale  = (float*)(ws + 16 * MiB);
    float* Qf = out;
    float* Kf = out + (size_t)B * F;

    dim3 tb(32, 8);
    transpose_cast_kernel<<<dim3(F / 32, D / 32), tb, 0, stream>>>(Wq, WqT, D, F);
    transpose_cast_kernel<<<dim3(F / 32, D / 32), tb, 0, stream>>>(Wk, WkT, D, F);
    transpose_cast_kernel<<<dim3(D / 32, D / 32), tb, 0, stream>>>(Wv, WvT, D, D);

    gemm2<0, false, false><<<dim3(F / 128, B / 128), 256, 0, stream>>>(
        Q, WqT, WqT, bq, bq, 1 << 30, nullptr, Qf, D, F);
    gemm2<0, false, false><<<dim3(F / 128, B / 128), 256, 0, stream>>>(
        K_, WkT, WkT, bk, bk, 1 << 30, nullptr, Kf, D, F);
    reduce_scale2<false><<<B, 256, 0, stream>>>(Qf, Kf, scale);
    gemm2<1, false, false><<<dim3(D / 128, B / 128), 256, 0, stream>>>(
        V, WvT, WvT, bv, bv, 1 << 30, scale, out, D, D);
  }
}

// Round 4
// 394.541 us; speedup vs baseline: 2.1521x; 1.1179x over previous
//
#include <hip/hip_runtime.h>
#include <hip/hip_fp16.h>
#include <cstdint>
#include <cstddef>

typedef _Float16 f16x8 __attribute__((ext_vector_type(8)));
typedef _Float16 f16x4 __attribute__((ext_vector_type(4)));
typedef float    f32x4 __attribute__((ext_vector_type(4)));

#define GPTR(p) ((const __attribute__((address_space(1))) void*)(p))
#define SPTR(p) ((__attribute__((address_space(3))) void*)(p))

// ---------------------------------------------------------------------------
// Transpose + cast fp32 -> fp16 : W (R x C) row-major -> Wt (C x R) row-major
// ---------------------------------------------------------------------------
__global__ void transpose_cast_kernel(const float* __restrict__ W,
                                      _Float16* __restrict__ Wt,
                                      int R, int C) {
  __shared__ float tile[32][33];
  const int c  = blockIdx.x * 32 + threadIdx.x;
  const int r0 = blockIdx.y * 32;
  for (int i = threadIdx.y; i < 32; i += 8)
    tile[i][threadIdx.x] = W[(size_t)(r0 + i) * C + c];
  __syncthreads();
  const int out_c = r0 + threadIdx.x;   // new col = old row
  const int oc0   = blockIdx.x * 32;    // new row = old col
  for (int i = threadIdx.y; i < 32; i += 8)
    Wt[(size_t)(oc0 + i) * R + out_c] = (_Float16)tile[threadIdx.x][i];
}

// ---------------------------------------------------------------------------
// Flat cast fp32 -> fp16, float4 granularity
// ---------------------------------------------------------------------------
__global__ void cast_f32_f16_kernel(const float* __restrict__ src,
                                    _Float16* __restrict__ dst) {
  const size_t i = (size_t)blockIdx.x * 256 + threadIdx.x;
  const float4 v = ((const float4*)src)[i];
  f16x4 h;
  h[0] = (_Float16)v.x; h[1] = (_Float16)v.y;
  h[2] = (_Float16)v.z; h[3] = (_Float16)v.w;
  ((f16x4*)dst)[i] = h;
}

// ---------------------------------------------------------------------------
// 256x256 deep-pipelined GEMM, 8 waves, BK=32, 3-tile prefetch ring,
// ONE barrier per K-tile window (round-4 schedule).
//   C(MxN) = A(MxK fp16) @ Bt(NxK fp16)^T + bias
//   MODE 0: C = elu(acc + bias)           MODE 1: C = scale[row]*(acc + bias)
// Round-4 change vs round-3 (which measured 3937 cyc/window vs 1230 MFMA
// floor; 4 barriers/window + post-barrier ds_reads serialized every wave):
//   - Window = {12 ds_reads batched; MFMA-lo x16; stage(t+3); MFMA-hi x16;
//     vmcnt(8); s_barrier}. ONE barrier per window. The compiler's counted
//     lgkmcnt lets afH reads overlap MFMA-lo; the vmcnt wait for tile t+1
//     hides under MFMA-hi; stage-issue hides under the MFMA shadow.
//   - Single-barrier safety: a wave stages(t+3) (overwriting t-1's slots)
//     only after barrier(t-1); any wave past barrier(t-1) implies all waves
//     arrived there, and each wave's t-1 reads were lgkm-drained before its
//     own MFMAs, which precede its barrier arrival. Read validity of tile t:
//     per-wave vmcnt(8) + barrier at end of W(t-1).
//   - vmcnt never drains mid-loop (8 steady; 4/0 only in last 3 windows).
//   - ring: 8 half-tile slots per operand (8 KiB each), 128 KiB LDS total,
//     tiles t..t+3 resident; pair-swizzle layout (0 bank conflicts measured).
//   - 512 thr = 8 waves (2M x 4N), per-wave 128x64, acc[8][4] in AGPRs
//     (VGPR_Count 128 measured in round 3 -> 2 waves/SIMD).
//   - bijective XCD swizzle kept (FETCH 266MB -> 49.5MB measured).
// ---------------------------------------------------------------------------
#define STG8(kk, h, slotv) do {                                                \
    __builtin_amdgcn_global_load_lds(GPTR(aRow + (h) * hstep + (kk)),          \
        SPTR(Aring + (slotv) * 4096 + wave * 512), 16, 0, 0);                  \
    __builtin_amdgcn_global_load_lds(GPTR(bRow + (h) * hstep + (kk)),          \
        SPTR(Bring + (slotv) * 4096 + wave * 512), 16, 0, 0);                  \
  } while (0)

#define WINDOW8(t_, DOSTG, DOWAIT, VCSTR) do {                                 \
    const int e_ = (2 * (t_)) & 7;                                             \
    const _Float16* Ab_ = Aring + ((e_ + wm) & 7) * 4096;                      \
    const _Float16* Bb_ = Bring + ((e_ + (wn >> 1)) & 7) * 4096                \
                          + (wn & 1) * 2048;                                   \
    f16x8 bf_[4], afL_[4], afH_[4];                                            \
    _Pragma("unroll")                                                          \
    for (int j_ = 0; j_ < 4; ++j_)                                             \
      bf_[j_] = *(const f16x8*)(Bb_ + j_ * 512 + lane_c * 8);                  \
    _Pragma("unroll")                                                          \
    for (int i_ = 0; i_ < 4; ++i_)                                             \
      afL_[i_] = *(const f16x8*)(Ab_ + i_ * 512 + lane_c * 8);                 \
    _Pragma("unroll")                                                          \
    for (int i_ = 0; i_ < 4; ++i_)                                             \
      afH_[i_] = *(const f16x8*)(Ab_ + (i_ + 4) * 512 + lane_c * 8);           \
    __builtin_amdgcn_s_setprio(1);                                             \
    _Pragma("unroll")                                                          \
    for (int i_ = 0; i_ < 4; ++i_)                                             \
      _Pragma("unroll")                                                        \
      for (int j_ = 0; j_ < 4; ++j_)                                           \
        acc[i_][j_] = __builtin_amdgcn_mfma_f32_16x16x32_f16(afL_[i_], bf_[j_],\
                                                             acc[i_][j_],      \
                                                             0, 0, 0);         \
    if (DOSTG) {                                                               \
      STG8(((t_) + 3) * 32, 0, (e_ + 6) & 7);                                  \
      STG8(((t_) + 3) * 32, 1, (e_ + 7) & 7);                                  \
    }                                                                          \
    _Pragma("unroll")                                                          \
    for (int i_ = 0; i_ < 4; ++i_)                                             \
      _Pragma("unroll")                                                        \
      for (int j_ = 0; j_ < 4; ++j_)                                           \
        acc[i_ + 4][j_] = __builtin_amdgcn_mfma_f32_16x16x32_f16(afH_[i_],     \
                                                                 bf_[j_],      \
                                                                 acc[i_ + 4][j_],\
                                                                 0, 0, 0);     \
    __builtin_amdgcn_s_setprio(0);                                             \
    if (DOWAIT) asm volatile("s_waitcnt vmcnt(" VCSTR ")" ::: "memory");       \
    __builtin_amdgcn_s_barrier();                                              \
    asm volatile("" ::: "memory");                                             \
  } while (0)

template <int MODE, bool OUTHALF>
__global__ __launch_bounds__(512, 2) void gemm8p(
    const _Float16* __restrict__ A,
    const _Float16* __restrict__ Bt0, const _Float16* __restrict__ Bt1,
    const float* __restrict__ bias0, const float* __restrict__ bias1,
    int msplit, const float* __restrict__ scale,
    void* __restrict__ Cv, int K, int N) {
  // 8 half-tile slots per operand, 8 KiB (4096 halves) each: 128 KiB total.
  __shared__ __align__(16) _Float16 Aring[8 * 4096];
  __shared__ __align__(16) _Float16 Bring[8 * 4096];

  const int tid  = threadIdx.x;
  const int lane = tid & 63;
  const int wave = tid >> 6;       // 0..7
  const int quad = lane >> 4;
  const int r    = lane & 15;
  const int wm   = wave >> 2;      // 0..1  (M half)
  const int wn   = wave & 3;       // 0..3  (N quarter)

  // Bijective XCD-aware block swizzle (both grids: 256 blocks, %8 == 0).
  const int gx  = gridDim.x;
  const int nwg = gx * gridDim.y;
  int flat = blockIdx.y * gx + blockIdx.x;
  if ((nwg & 7) == 0) flat = (flat & 7) * (nwg >> 3) + (flat >> 3);
  const int m0 = (flat / gx) * 256;
  const int n0 = (flat % gx) * 256;

  const _Float16* Bt   = (m0 >= msplit) ? Bt1 : Bt0;
  const float*    bias = (m0 >= msplit) ? bias1 : bias0;

  // Per-thread staging source (pair-swizzle): 16B slot s = tid.
  const int sp  = tid >> 3;
  const int sub = (tid & 7) ^ (sp & 7);
  const int lr  = sp * 2 + (sub >> 2);   // local row in the 128-row half
  const int sc  = sub & 3;               // k-chunk (8 halves)
  const _Float16* aRow = A  + (size_t)(m0 + lr) * K + sc * 8;
  const _Float16* bRow = Bt + (size_t)(n0 + lr) * K + sc * 8;
  const int hstep = 128 * K;             // elements: half 0 -> half 1

  // Per-lane read constant: frag (lr=i*16+r, c=quad) lives at 16B slot
  // i*64 + lane_c, lane_c = (r>>1)*8 + ((((r&1)<<2)|quad) ^ (r>>1)).
  const int lane_c = (r >> 1) * 8 + (((((r & 1) << 2) | quad)) ^ (r >> 1));

  f32x4 acc[8][4] = {};
  const int NT = K >> 5;   // K/32 = 64 here (>= 4 required)

  // Prologue: stage tiles 0,1,2 (12 loads/thread, in order).
#pragma unroll
  for (int tt = 0; tt < 3; ++tt) {
    STG8(tt * 32, 0, (2 * tt) & 7);
    STG8(tt * 32, 1, (2 * tt + 1) & 7);
  }
  asm volatile("s_waitcnt vmcnt(8)" ::: "memory");   // tile 0 landed
  __builtin_amdgcn_s_barrier();
  asm volatile("" ::: "memory");

  for (int t = 0; t < NT - 3; ++t) WINDOW8(t, 1, 1, "8");
  WINDOW8(NT - 3, 0, 1, "4");
  WINDOW8(NT - 2, 0, 1, "0");
  WINDOW8(NT - 1, 0, 0, "0");

  // Epilogue: C/D layout col = lane&15, row = quad*4 + reg.
  float*    Cf = (float*)Cv;
  _Float16* Ch = (_Float16*)Cv;
#pragma unroll
  for (int i = 0; i < 8; ++i) {
    const int row0 = m0 + wm * 128 + i * 16 + quad * 4;
#pragma unroll
    for (int j = 0; j < 4; ++j) {
      const int col = n0 + wn * 64 + j * 16 + r;
      const float b = bias[col];
#pragma unroll
      for (int reg = 0; reg < 4; ++reg) {
        const int row = row0 + reg;
        float v = acc[i][j][reg] + b;
        if (MODE == 0) v = v > 0.f ? v : (expf(v) - 1.f);  // ELU (no +1)
        else           v = v * scale[row];
        if (OUTHALF) Ch[(size_t)row * N + col] = (_Float16)v;
        else         Cf[(size_t)row * N + col] = v;
      }
    }
  }
}

#undef STG8
#undef WINDOW8

// ---------------------------------------------------------------------------
// Legacy 128x128 GEMM kept for the small-workspace fallback path.
// ---------------------------------------------------------------------------
template <int MODE, bool AHALF, bool OUTHALF>
__global__ __launch_bounds__(256) void gemm2(
    const void* __restrict__ Av,
    const _Float16* __restrict__ Bt0, const _Float16* __restrict__ Bt1,
    const float* __restrict__ bias0, const float* __restrict__ bias1,
    int msplit, const float* __restrict__ scale,
    void* __restrict__ Cv, int K, int N) {
  constexpr int BK = 64;
  __shared__ __align__(16) _Float16 As[128 * BK];
  __shared__ __align__(16) _Float16 Bs[128 * BK];

  const int tid  = threadIdx.x;
  const int lane = tid & 63;
  const int wave = tid >> 6;
  const int quad = lane >> 4;
  const int r    = lane & 15;
  const int wm   = wave >> 1;
  const int wn   = wave & 1;
  const int m0   = blockIdx.y * 128;
  const int n0   = blockIdx.x * 128;

  const _Float16* Bt  = (m0 >= msplit) ? Bt1 : Bt0;
  const float* bias   = (m0 >= msplit) ? bias1 : bias0;

  size_t aoff[4], boff[4];
  int slot[4];
#pragma unroll
  for (int t = 0; t < 4; ++t) {
    const int s  = wave * 256 + t * 64 + lane;
    const int n  = s >> 3;
    const int kc = (s & 7) ^ (n & 7);
    aoff[t] = (size_t)(m0 + n) * K + kc * 8;
    boff[t] = (size_t)(n0 + n) * K + kc * 8;
    slot[t] = s;
  }

  f32x4 acc[4][4] = {};
  const _Float16* Ah = (const _Float16*)Av;
  const float*    Af = (const float*)Av;

  for (int k0 = 0; k0 < K; k0 += BK) {
    __syncthreads();
    if (AHALF) {
#pragma unroll
      for (int t = 0; t < 4; ++t)
        __builtin_amdgcn_global_load_lds(GPTR(Ah + aoff[t] + k0),
                                         SPTR(As + (wave * 256 + t * 64) * 8),
                                         16, 0, 0);
    } else {
#pragma unroll
      for (int t = 0; t < 4; ++t) {
        const float* ap = Af + aoff[t] + k0;
        const float4 v0 = *(const float4*)ap;
        const float4 v1 = *(const float4*)(ap + 4);
        f16x8 h;
        h[0] = (_Float16)v0.x; h[1] = (_Float16)v0.y;
        h[2] = (_Float16)v0.z; h[3] = (_Float16)v0.w;
        h[4] = (_Float16)v1.x; h[5] = (_Float16)v1.y;
        h[6] = (_Float16)v1.z; h[7] = (_Float16)v1.w;
        *(f16x8*)(As + (size_t)slot[t] * 8) = h;
      }
    }
#pragma unroll
    for (int t = 0; t < 4; ++t)
      __builtin_amdgcn_global_load_lds(GPTR(Bt + boff[t] + k0),
                                       SPTR(Bs + (wave * 256 + t * 64) * 8),
                                       16, 0, 0);
    __syncthreads();

#pragma unroll
    for (int ki = 0; ki < 2; ++ki) {
      f16x8 af[4], bf[4];
#pragma unroll
      for (int i = 0; i < 4; ++i) {
        const int an = wm * 64 + i * 16 + r;
        af[i] = *(const f16x8*)(As + (an * 8 + ((ki * 4 + quad) ^ (an & 7))) * 8);
      }
#pragma unroll
      for (int j = 0; j < 4; ++j) {
        const int bn = wn * 64 + j * 16 + r;
        bf[j] = *(const f16x8*)(Bs + (bn * 8 + ((ki * 4 + quad) ^ (bn & 7))) * 8);
      }
#pragma unroll
      for (int i = 0; i < 4; ++i)
#pragma unroll
        for (int j = 0; j < 4; ++j)
          acc[i][j] = __builtin_amdgcn_mfma_f32_16x16x32_f16(af[i], bf[j],
                                                             acc[i][j], 0, 0, 0);
    }
  }

  float*    Cf = (float*)Cv;
  _Float16* Ch = (_Float16*)Cv;
#pragma unroll
  for (int i = 0; i < 4; ++i) {
#pragma unroll
    for (int j = 0; j < 4; ++j) {
      const int col = n0 + wn * 64 + j * 16 + r;
      const float b = bias[col];
#pragma unroll
      for (int reg = 0; reg < 4; ++reg) {
        const int row = m0 + wm * 64 + i * 16 + quad * 4 + reg;
        float v = acc[i][j][reg] + b;
        if (MODE == 0) v = v > 0.f ? v : (expf(v) - 1.f);
        else           v = v * scale[row];
        if (OUTHALF) Ch[(size_t)row * N + col] = (_Float16)v;
        else         Cf[(size_t)row * N + col] = v;
      }
    }
  }
}

// ---------------------------------------------------------------------------
// scale[b] = (Qf[b].Kf[b]) / (sum(Qf[b]) * sum(Kf[b]) + eps), F = 1024.
// ---------------------------------------------------------------------------
template <bool HALF>
__global__ void reduce_scale2(const void* __restrict__ Qf,
                              const void* __restrict__ Kf,
                              float* __restrict__ scale) {
  const int b = blockIdx.x;
  const int t = threadIdx.x;
  float q[4], k[4];
  if (HALF) {
    const f16x4 qh = ((const f16x4*)((const _Float16*)Qf + (size_t)b * 1024))[t];
    const f16x4 kh = ((const f16x4*)((const _Float16*)Kf + (size_t)b * 1024))[t];
#pragma unroll
    for (int i = 0; i < 4; ++i) { q[i] = (float)qh[i]; k[i] = (float)kh[i]; }
  } else {
    const float4 qv = ((const float4*)((const float*)Qf + (size_t)b * 1024))[t];
    const float4 kv = ((const float4*)((const float*)Kf + (size_t)b * 1024))[t];
    q[0] = qv.x; q[1] = qv.y; q[2] = qv.z; q[3] = qv.w;
    k[0] = kv.x; k[1] = kv.y; k[2] = kv.z; k[3] = kv.w;
  }
  float qk = q[0] * k[0] + q[1] * k[1] + q[2] * k[2] + q[3] * k[3];
  float sq = q[0] + q[1] + q[2] + q[3];
  float sk = k[0] + k[1] + k[2] + k[3];
#pragma unroll
  for (int off = 32; off > 0; off >>= 1) {
    qk += __shfl_down(qk, off, 64);
    sq += __shfl_down(sq, off, 64);
    sk += __shfl_down(sk, off, 64);
  }
  __shared__ float buf[3][4];
  const int lane = t & 63, wv = t >> 6;
  if (lane == 0) { buf[0][wv] = qk; buf[1][wv] = sq; buf[2][wv] = sk; }
  __syncthreads();
  if (t == 0) {
    const float QK = buf[0][0] + buf[0][1] + buf[0][2] + buf[0][3];
    const float SQ = buf[1][0] + buf[1][1] + buf[1][2] + buf[1][3];
    const float SK = buf[2][0] + buf[2][1] + buf[2][2] + buf[2][3];
    scale[b] = QK / (SQ * SK + 1e-6f);
  }
}

// ---------------------------------------------------------------------------
extern "C" void kernel_launch(void* const* d_in, const int* in_sizes, int n_in,
                              void* d_out, int out_size, void* d_ws,
                              size_t ws_size, hipStream_t stream) {
  const float* Q  = (const float*)d_in[0];
  const float* K_ = (const float*)d_in[1];
  const float* V  = (const float*)d_in[2];
  const float* Wq = (const float*)d_in[3];
  const float* bq = (const float*)d_in[4];
  const float* Wk = (const float*)d_in[5];
  const float* bk = (const float*)d_in[6];
  const float* Wv = (const float*)d_in[7];
  const float* bv = (const float*)d_in[8];
  float* out = (float*)d_out;

  const int B = 8192, D = 2048, F = 1024;
  const size_t MiB = 1u << 20;
  char* ws = (char*)d_ws;

  // Fast path ws layout:
  //   [0, 8M):    WqT(4M)+WkT(4M); later WvT(8M) overwrites (after feat GEMM)
  //   [8M, 40M):  QfH(16M)+KfH(16M) contiguous; later Vh(32M) overwrites
  //   [40M, +32K): scale
  const size_t NEED_FAST = 40 * MiB + 64 * 1024;

  if (ws_size >= NEED_FAST) {
    _Float16* WqT = (_Float16*)ws;
    _Float16* WkT = (_Float16*)(ws + 4 * MiB);
    _Float16* WvT = (_Float16*)ws;             // reuses weight region
    _Float16* QfH = (_Float16*)(ws + 8 * MiB);
    _Float16* KfH = (_Float16*)(ws + 24 * MiB);
    _Float16* Vh  = (_Float16*)(ws + 8 * MiB); // reuses feature region
    float* scale  = (float*)(ws + 40 * MiB);
    _Float16* Qh = (_Float16*)d_out;                  // d_out as fp16 scratch
    _Float16* Kh = (_Float16*)d_out + (size_t)B * D;  // adjacent -> stacked M

    dim3 tb(32, 8);
    transpose_cast_kernel<<<dim3(F / 32, D / 32), tb, 0, stream>>>(Wq, WqT, D, F);
    transpose_cast_kernel<<<dim3(F / 32, D / 32), tb, 0, stream>>>(Wk, WkT, D, F);
    const int castBlocks = (B * D / 4) / 256;  // 16384
    cast_f32_f16_kernel<<<castBlocks, 256, 0, stream>>>(Q,  Qh);
    cast_f32_f16_kernel<<<castBlocks, 256, 0, stream>>>(K_, Kh);

    // Stacked feature GEMM: M = 16384 ([Qh;Kh]), split at 8192 selects
    // Wq/bq vs Wk/bk. Grid 4x64 = 256 blocks = 1/CU, 512 thr, 128 KiB LDS.
    gemm8p<0, true><<<dim3(F / 256, (2 * B) / 256), 512, 0, stream>>>(
        Qh, WqT, WkT, bq, bk, B, nullptr, QfH, D, F);
    reduce_scale2<true><<<B, 256, 0, stream>>>(QfH, KfH, scale);

    cast_f32_f16_kernel<<<castBlocks, 256, 0, stream>>>(V, Vh);
    transpose_cast_kernel<<<dim3(D / 32, D / 32), tb, 0, stream>>>(Wv, WvT, D, D);
    gemm8p<1, false><<<dim3(D / 256, B / 256), 512, 0, stream>>>(
        Vh, WvT, WvT, bv, bv, 1 << 30, scale, out, D, D);
  } else {
    // Fallback: fp32 A staging in-kernel, Qf/Kf fp32 in d_out.
    _Float16* WqT = (_Float16*)ws;
    _Float16* WkT = (_Float16*)(ws + 4 * MiB);
    _Float16* WvT = (_Float16*)(ws + 8 * MiB);
    float* scale  = (float*)(ws + 16 * MiB);
    float* Qf = out;
    float* Kf = out + (size_t)B * F;

    dim3 tb(32, 8);
    transpose_cast_kernel<<<dim3(F / 32, D / 32), tb, 0, stream>>>(Wq, WqT, D, F);
    transpose_cast_kernel<<<dim3(F / 32, D / 32), tb, 0, stream>>>(Wk, WkT, D, F);
    transpose_cast_kernel<<<dim3(D / 32, D / 32), tb, 0, stream>>>(Wv, WvT, D, D);

    gemm2<0, false, false><<<dim3(F / 128, B / 128), 256, 0, stream>>>(
        Q, WqT, WqT, bq, bq, 1 << 30, nullptr, Qf, D, F);
    gemm2<0, false, false><<<dim3(F / 128, B / 128), 256, 0, stream>>>(
        K_, WkT, WkT, bk, bk, 1 << 30, nullptr, Kf, D, F);
    reduce_scale2<false><<<B, 256, 0, stream>>>(Qf, Kf, scale);
    gemm2<1, false, false><<<dim3(D / 128, B / 128), 256, 0, stream>>>(
        V, WvT, WvT, bv, bv, 1 << 30, scale, out, D, D);
  }
}

// Round 5
// 393.260 us; speedup vs baseline: 2.1591x; 1.0033x over previous
//
#include <hip/hip_runtime.h>
#include <hip/hip_fp16.h>
#include <cstdint>
#include <cstddef>

typedef _Float16 f16x8 __attribute__((ext_vector_type(8)));
typedef _Float16 f16x4 __attribute__((ext_vector_type(4)));
typedef float    f32x4 __attribute__((ext_vector_type(4)));

#define GPTR(p) ((const __attribute__((address_space(1))) void*)(p))
#define SPTR(p) ((__attribute__((address_space(3))) void*)(p))

// ---------------------------------------------------------------------------
// Transpose + cast fp32 -> fp16 : W (R x C) row-major -> Wt (C x R) row-major
// ---------------------------------------------------------------------------
__global__ void transpose_cast_kernel(const float* __restrict__ W,
                                      _Float16* __restrict__ Wt,
                                      int R, int C) {
  __shared__ float tile[32][33];
  const int c  = blockIdx.x * 32 + threadIdx.x;
  const int r0 = blockIdx.y * 32;
  for (int i = threadIdx.y; i < 32; i += 8)
    tile[i][threadIdx.x] = W[(size_t)(r0 + i) * C + c];
  __syncthreads();
  const int out_c = r0 + threadIdx.x;   // new col = old row
  const int oc0   = blockIdx.x * 32;    // new row = old col
  for (int i = threadIdx.y; i < 32; i += 8)
    Wt[(size_t)(oc0 + i) * R + out_c] = (_Float16)tile[threadIdx.x][i];
}

// Two transposes in one launch (blockIdx.z selects) -- saves a launch.
__global__ void transpose_cast2_kernel(const float* __restrict__ W0,
                                       _Float16* __restrict__ Wt0,
                                       const float* __restrict__ W1,
                                       _Float16* __restrict__ Wt1,
                                       int R, int C) {
  const float* __restrict__ W  = blockIdx.z ? W1  : W0;
  _Float16*    __restrict__ Wt = blockIdx.z ? Wt1 : Wt0;
  __shared__ float tile[32][33];
  const int c  = blockIdx.x * 32 + threadIdx.x;
  const int r0 = blockIdx.y * 32;
  for (int i = threadIdx.y; i < 32; i += 8)
    tile[i][threadIdx.x] = W[(size_t)(r0 + i) * C + c];
  __syncthreads();
  const int out_c = r0 + threadIdx.x;
  const int oc0   = blockIdx.x * 32;
  for (int i = threadIdx.y; i < 32; i += 8)
    Wt[(size_t)(oc0 + i) * R + out_c] = (_Float16)tile[threadIdx.x][i];
}

// ---------------------------------------------------------------------------
// Flat cast fp32 -> fp16, float4 granularity
// ---------------------------------------------------------------------------
__global__ void cast_f32_f16_kernel(const float* __restrict__ src,
                                    _Float16* __restrict__ dst) {
  const size_t i = (size_t)blockIdx.x * 256 + threadIdx.x;
  const float4 v = ((const float4*)src)[i];
  f16x4 h;
  h[0] = (_Float16)v.x; h[1] = (_Float16)v.y;
  h[2] = (_Float16)v.z; h[3] = (_Float16)v.w;
  ((f16x4*)dst)[i] = h;
}

// Two sources -> one contiguous fp16 dest (Qh|Kh); half4 % 256 == 0 so the
// branch is block-uniform. Saves a launch.
__global__ void cast2_f32_f16_kernel(const float* __restrict__ s0,
                                     const float* __restrict__ s1,
                                     _Float16* __restrict__ dst, int half4) {
  const int i = blockIdx.x * 256 + threadIdx.x;
  const float4 v = (i < half4) ? ((const float4*)s0)[i]
                               : ((const float4*)s1)[i - half4];
  f16x4 h;
  h[0] = (_Float16)v.x; h[1] = (_Float16)v.y;
  h[2] = (_Float16)v.z; h[3] = (_Float16)v.w;
  ((f16x4*)dst)[i] = h;
}

// ---------------------------------------------------------------------------
// 256x256 deep-pipelined GEMM, 8 waves, BK=32, 3-tile prefetch ring,
// TWO-phase window with reads-BEFORE-barrier (round-5 / m201 phase pattern).
//   C(MxN) = A(MxK fp16) @ Bt(NxK fp16)^T + bias
//   MODE 0: C = elu(acc + bias)           MODE 1: C = scale[row]*(acc + bias)
// Round-5 change vs round-4 (single barrier, reads after it: every
// barrier-synced wave ate the full LDS-read latency serially; 2764 cyc/window
// measured vs ~1200 of work):
//   - phase A: {ds_read bf+afL (8); stage(t+3)-lo; BARRIER; MFMA-lo x16}
//     phase B: {ds_read afH (4);   stage(t+3)-hi; vmcnt(8); BARRIER; MFMA-hi}
//     Reads are issued BEFORE each barrier so their latency hides under the
//     barrier wait; MFMA starts immediately after. (m201's key ordering.)
//   - Race-freedom: STG-lo(t+3) overwrites tile t-1-lo, whose readers
//     (bf/afL of window t-1) drained before MFMA-lo(t-1), which precedes
//     barrier-B(t-1) -- and STG-lo is issued after barrier-B(t-1). STG-hi
//     (t+3) is issued after barrier-A(t), by which point every wave finished
//     MFMA-hi(t-1), draining its t-1-hi reads. vmcnt(8) confirms tile t+1
//     (12 outstanding -> 8) and never drains mid-loop.
//   - ring: 8 half-tile slots per operand (8 KiB each), 128 KiB LDS total,
//     tiles t..t+3 resident; pair-swizzle layout (0 bank conflicts measured).
//   - 512 thr = 8 waves (2M x 4N), per-wave 128x64, acc[8][4] in AGPRs;
//     128 VGPR + 128 AGPR = exactly the 2-waves/SIMD budget (no headroom:
//     register double-buffering of fragments is impossible at this tile).
//   - bijective XCD swizzle kept (FETCH 266MB -> 49.5MB measured).
// ---------------------------------------------------------------------------
#define STG8(kk, h, slotv) do {                                                \
    __builtin_amdgcn_global_load_lds(GPTR(aRow + (h) * hstep + (kk)),          \
        SPTR(Aring + (slotv) * 4096 + wave * 512), 16, 0, 0);                  \
    __builtin_amdgcn_global_load_lds(GPTR(bRow + (h) * hstep + (kk)),          \
        SPTR(Bring + (slotv) * 4096 + wave * 512), 16, 0, 0);                  \
  } while (0)

#define WINDOW8(t_, DOSTG, DOWAIT, VCSTR) do {                                 \
    const int e_ = (2 * (t_)) & 7;                                             \
    const _Float16* Ab_ = Aring + ((e_ + wm) & 7) * 4096;                      \
    const _Float16* Bb_ = Bring + ((e_ + (wn >> 1)) & 7) * 4096                \
                          + (wn & 1) * 2048;                                   \
    f16x8 bf_[4], afL_[4], afH_[4];                                            \
    /* ---- phase A: reads first, then stage, then barrier ---- */             \
    _Pragma("unroll")                                                          \
    for (int j_ = 0; j_ < 4; ++j_)                                             \
      bf_[j_] = *(const f16x8*)(Bb_ + j_ * 512 + lane_c * 8);                  \
    _Pragma("unroll")                                                          \
    for (int i_ = 0; i_ < 4; ++i_)                                             \
      afL_[i_] = *(const f16x8*)(Ab_ + i_ * 512 + lane_c * 8);                 \
    if (DOSTG) STG8(((t_) + 3) * 32, 0, (e_ + 6) & 7);                         \
    __builtin_amdgcn_s_barrier();                                              \
    asm volatile("" ::: "memory");                                             \
    __builtin_amdgcn_s_setprio(1);                                             \
    _Pragma("unroll")                                                          \
    for (int i_ = 0; i_ < 4; ++i_)                                             \
      _Pragma("unroll")                                                        \
      for (int j_ = 0; j_ < 4; ++j_)                                           \
        acc[i_][j_] = __builtin_amdgcn_mfma_f32_16x16x32_f16(afL_[i_], bf_[j_],\
                                                             acc[i_][j_],      \
                                                             0, 0, 0);         \
    __builtin_amdgcn_s_setprio(0);                                             \
    /* ---- phase B: reads first, then stage, vmcnt, barrier ---- */           \
    _Pragma("unroll")                                                          \
    for (int i_ = 0; i_ < 4; ++i_)                                             \
      afH_[i_] = *(const f16x8*)(Ab_ + (i_ + 4) * 512 + lane_c * 8);           \
    if (DOSTG) STG8(((t_) + 3) * 32, 1, (e_ + 7) & 7);                         \
    if (DOWAIT) asm volatile("s_waitcnt vmcnt(" VCSTR ")" ::: "memory");       \
    __builtin_amdgcn_s_barrier();                                              \
    asm volatile("" ::: "memory");                                             \
    __builtin_amdgcn_s_setprio(1);                                             \
    _Pragma("unroll")                                                          \
    for (int i_ = 0; i_ < 4; ++i_)                                             \
      _Pragma("unroll")                                                        \
      for (int j_ = 0; j_ < 4; ++j_)                                           \
        acc[i_ + 4][j_] = __builtin_amdgcn_mfma_f32_16x16x32_f16(afH_[i_],     \
                                                                 bf_[j_],      \
                                                                 acc[i_ + 4][j_],\
                                                                 0, 0, 0);     \
    __builtin_amdgcn_s_setprio(0);                                             \
  } while (0)

template <int MODE, bool OUTHALF>
__global__ __launch_bounds__(512, 2) void gemm8p(
    const _Float16* __restrict__ A,
    const _Float16* __restrict__ Bt0, const _Float16* __restrict__ Bt1,
    const float* __restrict__ bias0, const float* __restrict__ bias1,
    int msplit, const float* __restrict__ scale,
    void* __restrict__ Cv, int K, int N) {
  // 8 half-tile slots per operand, 8 KiB (4096 halves) each: 128 KiB total.
  __shared__ __align__(16) _Float16 Aring[8 * 4096];
  __shared__ __align__(16) _Float16 Bring[8 * 4096];

  const int tid  = threadIdx.x;
  const int lane = tid & 63;
  const int wave = tid >> 6;       // 0..7
  const int quad = lane >> 4;
  const int r    = lane & 15;
  const int wm   = wave >> 2;      // 0..1  (M half)
  const int wn   = wave & 3;       // 0..3  (N quarter)

  // Bijective XCD-aware block swizzle (both grids: 256 blocks, %8 == 0).
  const int gx  = gridDim.x;
  const int nwg = gx * gridDim.y;
  int flat = blockIdx.y * gx + blockIdx.x;
  if ((nwg & 7) == 0) flat = (flat & 7) * (nwg >> 3) + (flat >> 3);
  const int m0 = (flat / gx) * 256;
  const int n0 = (flat % gx) * 256;

  const _Float16* Bt   = (m0 >= msplit) ? Bt1 : Bt0;
  const float*    bias = (m0 >= msplit) ? bias1 : bias0;

  // Per-thread staging source (pair-swizzle): 16B slot s = tid.
  const int sp  = tid >> 3;
  const int sub = (tid & 7) ^ (sp & 7);
  const int lr  = sp * 2 + (sub >> 2);   // local row in the 128-row half
  const int sc  = sub & 3;               // k-chunk (8 halves)
  const _Float16* aRow = A  + (size_t)(m0 + lr) * K + sc * 8;
  const _Float16* bRow = Bt + (size_t)(n0 + lr) * K + sc * 8;
  const int hstep = 128 * K;             // elements: half 0 -> half 1

  // Per-lane read constant: frag (lr=i*16+r, c=quad) lives at 16B slot
  // i*64 + lane_c, lane_c = (r>>1)*8 + ((((r&1)<<2)|quad) ^ (r>>1)).
  const int lane_c = (r >> 1) * 8 + (((((r & 1) << 2) | quad)) ^ (r >> 1));

  f32x4 acc[8][4] = {};
  const int NT = K >> 5;   // K/32 = 64 here (>= 4 required)

  // Prologue: stage tiles 0,1,2 (12 loads/thread, in order).
#pragma unroll
  for (int tt = 0; tt < 3; ++tt) {
    STG8(tt * 32, 0, (2 * tt) & 7);
    STG8(tt * 32, 1, (2 * tt + 1) & 7);
  }
  asm volatile("s_waitcnt vmcnt(8)" ::: "memory");   // tile 0 landed
  __builtin_amdgcn_s_barrier();
  asm volatile("" ::: "memory");

  for (int t = 0; t < NT - 3; ++t) WINDOW8(t, 1, 1, "8");
  WINDOW8(NT - 3, 0, 1, "4");
  WINDOW8(NT - 2, 0, 1, "0");
  WINDOW8(NT - 1, 0, 0, "0");

  // Epilogue: C/D layout col = lane&15, row = quad*4 + reg.
  float*    Cf = (float*)Cv;
  _Float16* Ch = (_Float16*)Cv;
#pragma unroll
  for (int i = 0; i < 8; ++i) {
    const int row0 = m0 + wm * 128 + i * 16 + quad * 4;
#pragma unroll
    for (int j = 0; j < 4; ++j) {
      const int col = n0 + wn * 64 + j * 16 + r;
      const float b = bias[col];
#pragma unroll
      for (int reg = 0; reg < 4; ++reg) {
        const int row = row0 + reg;
        float v = acc[i][j][reg] + b;
        if (MODE == 0) v = v > 0.f ? v : (expf(v) - 1.f);  // ELU (no +1)
        else           v = v * scale[row];
        if (OUTHALF) Ch[(size_t)row * N + col] = (_Float16)v;
        else         Cf[(size_t)row * N + col] = v;
      }
    }
  }
}

#undef STG8
#undef WINDOW8

// ---------------------------------------------------------------------------
// Legacy 128x128 GEMM kept for the small-workspace fallback path.
// ---------------------------------------------------------------------------
template <int MODE, bool AHALF, bool OUTHALF>
__global__ __launch_bounds__(256) void gemm2(
    const void* __restrict__ Av,
    const _Float16* __restrict__ Bt0, const _Float16* __restrict__ Bt1,
    const float* __restrict__ bias0, const float* __restrict__ bias1,
    int msplit, const float* __restrict__ scale,
    void* __restrict__ Cv, int K, int N) {
  constexpr int BK = 64;
  __shared__ __align__(16) _Float16 As[128 * BK];
  __shared__ __align__(16) _Float16 Bs[128 * BK];

  const int tid  = threadIdx.x;
  const int lane = tid & 63;
  const int wave = tid >> 6;
  const int quad = lane >> 4;
  const int r    = lane & 15;
  const int wm   = wave >> 1;
  const int wn   = wave & 1;
  const int m0   = blockIdx.y * 128;
  const int n0   = blockIdx.x * 128;

  const _Float16* Bt  = (m0 >= msplit) ? Bt1 : Bt0;
  const float* bias   = (m0 >= msplit) ? bias1 : bias0;

  size_t aoff[4], boff[4];
  int slot[4];
#pragma unroll
  for (int t = 0; t < 4; ++t) {
    const int s  = wave * 256 + t * 64 + lane;
    const int n  = s >> 3;
    const int kc = (s & 7) ^ (n & 7);
    aoff[t] = (size_t)(m0 + n) * K + kc * 8;
    boff[t] = (size_t)(n0 + n) * K + kc * 8;
    slot[t] = s;
  }

  f32x4 acc[4][4] = {};
  const _Float16* Ah = (const _Float16*)Av;
  const float*    Af = (const float*)Av;

  for (int k0 = 0; k0 < K; k0 += BK) {
    __syncthreads();
    if (AHALF) {
#pragma unroll
      for (int t = 0; t < 4; ++t)
        __builtin_amdgcn_global_load_lds(GPTR(Ah + aoff[t] + k0),
                                         SPTR(As + (wave * 256 + t * 64) * 8),
                                         16, 0, 0);
    } else {
#pragma unroll
      for (int t = 0; t < 4; ++t) {
        const float* ap = Af + aoff[t] + k0;
        const float4 v0 = *(const float4*)ap;
        const float4 v1 = *(const float4*)(ap + 4);
        f16x8 h;
        h[0] = (_Float16)v0.x; h[1] = (_Float16)v0.y;
        h[2] = (_Float16)v0.z; h[3] = (_Float16)v0.w;
        h[4] = (_Float16)v1.x; h[5] = (_Float16)v1.y;
        h[6] = (_Float16)v1.z; h[7] = (_Float16)v1.w;
        *(f16x8*)(As + (size_t)slot[t] * 8) = h;
      }
    }
#pragma unroll
    for (int t = 0; t < 4; ++t)
      __builtin_amdgcn_global_load_lds(GPTR(Bt + boff[t] + k0),
                                       SPTR(Bs + (wave * 256 + t * 64) * 8),
                                       16, 0, 0);
    __syncthreads();

#pragma unroll
    for (int ki = 0; ki < 2; ++ki) {
      f16x8 af[4], bf[4];
#pragma unroll
      for (int i = 0; i < 4; ++i) {
        const int an = wm * 64 + i * 16 + r;
        af[i] = *(const f16x8*)(As + (an * 8 + ((ki * 4 + quad) ^ (an & 7))) * 8);
      }
#pragma unroll
      for (int j = 0; j < 4; ++j) {
        const int bn = wn * 64 + j * 16 + r;
        bf[j] = *(const f16x8*)(Bs + (bn * 8 + ((ki * 4 + quad) ^ (bn & 7))) * 8);
      }
#pragma unroll
      for (int i = 0; i < 4; ++i)
#pragma unroll
        for (int j = 0; j < 4; ++j)
          acc[i][j] = __builtin_amdgcn_mfma_f32_16x16x32_f16(af[i], bf[j],
                                                             acc[i][j], 0, 0, 0);
    }
  }

  float*    Cf = (float*)Cv;
  _Float16* Ch = (_Float16*)Cv;
#pragma unroll
  for (int i = 0; i < 4; ++i) {
#pragma unroll
    for (int j = 0; j < 4; ++j) {
      const int col = n0 + wn * 64 + j * 16 + r;
      const float b = bias[col];
#pragma unroll
      for (int reg = 0; reg < 4; ++reg) {
        const int row = m0 + wm * 64 + i * 16 + quad * 4 + reg;
        float v = acc[i][j][reg] + b;
        if (MODE == 0) v = v > 0.f ? v : (expf(v) - 1.f);
        else           v = v * scale[row];
        if (OUTHALF) Ch[(size_t)row * N + col] = (_Float16)v;
        else         Cf[(size_t)row * N + col] = v;
      }
    }
  }
}

// ---------------------------------------------------------------------------
// scale[b] = (Qf[b].Kf[b]) / (sum(Qf[b]) * sum(Kf[b]) + eps), F = 1024.
// ---------------------------------------------------------------------------
template <bool HALF>
__global__ void reduce_scale2(const void* __restrict__ Qf,
                              const void* __restrict__ Kf,
                              float* __restrict__ scale) {
  const int b = blockIdx.x;
  const int t = threadIdx.x;
  float q[4], k[4];
  if (HALF) {
    const f16x4 qh = ((const f16x4*)((const _Float16*)Qf + (size_t)b * 1024))[t];
    const f16x4 kh = ((const f16x4*)((const _Float16*)Kf + (size_t)b * 1024))[t];
#pragma unroll
    for (int i = 0; i < 4; ++i) { q[i] = (float)qh[i]; k[i] = (float)kh[i]; }
  } else {
    const float4 qv = ((const float4*)((const float*)Qf + (size_t)b * 1024))[t];
    const float4 kv = ((const float4*)((const float*)Kf + (size_t)b * 1024))[t];
    q[0] = qv.x; q[1] = qv.y; q[2] = qv.z; q[3] = qv.w;
    k[0] = kv.x; k[1] = kv.y; k[2] = kv.z; k[3] = kv.w;
  }
  float qk = q[0] * k[0] + q[1] * k[1] + q[2] * k[2] + q[3] * k[3];
  float sq = q[0] + q[1] + q[2] + q[3];
  float sk = k[0] + k[1] + k[2] + k[3];
#pragma unroll
  for (int off = 32; off > 0; off >>= 1) {
    qk += __shfl_down(qk, off, 64);
    sq += __shfl_down(sq, off, 64);
    sk += __shfl_down(sk, off, 64);
  }
  __shared__ float buf[3][4];
  const int lane = t & 63, wv = t >> 6;
  if (lane == 0) { buf[0][wv] = qk; buf[1][wv] = sq; buf[2][wv] = sk; }
  __syncthreads();
  if (t == 0) {
    const float QK = buf[0][0] + buf[0][1] + buf[0][2] + buf[0][3];
    const float SQ = buf[1][0] + buf[1][1] + buf[1][2] + buf[1][3];
    const float SK = buf[2][0] + buf[2][1] + buf[2][2] + buf[2][3];
    scale[b] = QK / (SQ * SK + 1e-6f);
  }
}

// ---------------------------------------------------------------------------
extern "C" void kernel_launch(void* const* d_in, const int* in_sizes, int n_in,
                              void* d_out, int out_size, void* d_ws,
                              size_t ws_size, hipStream_t stream) {
  const float* Q  = (const float*)d_in[0];
  const float* K_ = (const float*)d_in[1];
  const float* V  = (const float*)d_in[2];
  const float* Wq = (const float*)d_in[3];
  const float* bq = (const float*)d_in[4];
  const float* Wk = (const float*)d_in[5];
  const float* bk = (const float*)d_in[6];
  const float* Wv = (const float*)d_in[7];
  const float* bv = (const float*)d_in[8];
  float* out = (float*)d_out;

  const int B = 8192, D = 2048, F = 1024;
  const size_t MiB = 1u << 20;
  char* ws = (char*)d_ws;

  // Fast path ws layout:
  //   [0, 8M):    WqT(4M)+WkT(4M); later WvT(8M) overwrites (after feat GEMM)
  //   [8M, 40M):  QfH(16M)+KfH(16M) contiguous; later Vh(32M) overwrites
  //   [40M, +32K): scale
  const size_t NEED_FAST = 40 * MiB + 64 * 1024;

  if (ws_size >= NEED_FAST) {
    _Float16* WqT = (_Float16*)ws;
    _Float16* WkT = (_Float16*)(ws + 4 * MiB);
    _Float16* WvT = (_Float16*)ws;             // reuses weight region
    _Float16* QfH = (_Float16*)(ws + 8 * MiB);
    _Float16* KfH = (_Float16*)(ws + 24 * MiB);
    _Float16* Vh  = (_Float16*)(ws + 8 * MiB); // reuses feature region
    float* scale  = (float*)(ws + 40 * MiB);
    _Float16* Qh = (_Float16*)d_out;                  // d_out as fp16 scratch
    _Float16* Kh = (_Float16*)d_out + (size_t)B * D;  // adjacent -> stacked M

    dim3 tb(32, 8);
    // Wq + Wk transposed in one launch (z selects).
    transpose_cast2_kernel<<<dim3(F / 32, D / 32, 2), tb, 0, stream>>>(
        Wq, WqT, Wk, WkT, D, F);
    // Q + K cast in one launch into contiguous Qh|Kh.
    const int half4 = B * D / 4;  // 4194304, % 256 == 0
    cast2_f32_f16_kernel<<<2 * half4 / 256, 256, 0, stream>>>(Q, K_, Qh, half4);

    // Stacked feature GEMM: M = 16384 ([Qh;Kh]), split at 8192 selects
    // Wq/bq vs Wk/bk. Grid 4x64 = 256 blocks = 1/CU, 512 thr, 128 KiB LDS.
    gemm8p<0, true><<<dim3(F / 256, (2 * B) / 256), 512, 0, stream>>>(
        Qh, WqT, WkT, bq, bk, B, nullptr, QfH, D, F);
    reduce_scale2<true><<<B, 256, 0, stream>>>(QfH, KfH, scale);

    cast_f32_f16_kernel<<<half4 / 256, 256, 0, stream>>>(V, Vh);
    transpose_cast_kernel<<<dim3(D / 32, D / 32), tb, 0, stream>>>(Wv, WvT, D, D);
    gemm8p<1, false><<<dim3(D / 256, B / 256), 512, 0, stream>>>(
        Vh, WvT, WvT, bv, bv, 1 << 30, scale, out, D, D);
  } else {
    // Fallback: fp32 A staging in-kernel, Qf/Kf fp32 in d_out.
    _Float16* WqT = (_Float16*)ws;
    _Float16* WkT = (_Float16*)(ws + 4 * MiB);
    _Float16* WvT = (_Float16*)(ws + 8 * MiB);
    float* scale  = (float*)(ws + 16 * MiB);
    float* Qf = out;
    float* Kf = out + (size_t)B * F;

    dim3 tb(32, 8);
    transpose_cast_kernel<<<dim3(F / 32, D / 32), tb, 0, stream>>>(Wq, WqT, D, F);
    transpose_cast_kernel<<<dim3(F / 32, D / 32), tb, 0, stream>>>(Wk, WkT, D, F);
    transpose_cast_kernel<<<dim3(D / 32, D / 32), tb, 0, stream>>>(Wv, WvT, D, D);

    gemm2<0, false, false><<<dim3(F / 128, B / 128), 256, 0, stream>>>(
        Q, WqT, WqT, bq, bq, 1 << 30, nullptr, Qf, D, F);
    gemm2<0, false, false><<<dim3(F / 128, B / 128), 256, 0, stream>>>(
        K_, WkT, WkT, bk, bk, 1 << 30, nullptr, Kf, D, F);
    reduce_scale2<false><<<B, 256, 0, stream>>>(Qf, Kf, scale);
    gemm2<1, false, false><<<dim3(D / 128, B / 128), 256, 0, stream>>>(
        V, WvT, WvT, bv, bv, 1 << 30, scale, out, D, D);
  }
}

// Round 6
// 379.448 us; speedup vs baseline: 2.2377x; 1.0364x over previous
//
#include <hip/hip_runtime.h>
#include <hip/hip_fp16.h>
#include <cstdint>
#include <cstddef>

typedef _Float16 f16x8 __attribute__((ext_vector_type(8)));
typedef _Float16 f16x4 __attribute__((ext_vector_type(4)));
typedef float    f32x4 __attribute__((ext_vector_type(4)));

#define GPTR(p) ((const __attribute__((address_space(1))) void*)(p))
#define SPTR(p) ((__attribute__((address_space(3))) void*)(p))

// ---------------------------------------------------------------------------
// Transpose + cast fp32 -> fp16 : W (R x C) row-major -> Wt (C x R) row-major
// (kept for fallback path)
// ---------------------------------------------------------------------------
__global__ void transpose_cast_kernel(const float* __restrict__ W,
                                      _Float16* __restrict__ Wt,
                                      int R, int C) {
  __shared__ float tile[32][33];
  const int c  = blockIdx.x * 32 + threadIdx.x;
  const int r0 = blockIdx.y * 32;
  for (int i = threadIdx.y; i < 32; i += 8)
    tile[i][threadIdx.x] = W[(size_t)(r0 + i) * C + c];
  __syncthreads();
  const int out_c = r0 + threadIdx.x;   // new col = old row
  const int oc0   = blockIdx.x * 32;    // new row = old col
  for (int i = threadIdx.y; i < 32; i += 8)
    Wt[(size_t)(oc0 + i) * R + out_c] = (_Float16)tile[threadIdx.x][i];
}

// ---------------------------------------------------------------------------
// Flat cast fp32 -> fp16, float4 granularity (fallback + split-V path)
// ---------------------------------------------------------------------------
__global__ void cast_f32_f16_kernel(const float* __restrict__ src,
                                    _Float16* __restrict__ dst) {
  const size_t i = (size_t)blockIdx.x * 256 + threadIdx.x;
  const float4 v = ((const float4*)src)[i];
  f16x4 h;
  h[0] = (_Float16)v.x; h[1] = (_Float16)v.y;
  h[2] = (_Float16)v.z; h[3] = (_Float16)v.w;
  ((f16x4*)dst)[i] = h;
}

// ---------------------------------------------------------------------------
// PREP (one launch, 36864 blocks x 256 thr), round-6 launch fusion:
//   blocks [0,2048)      : transpose+cast Wq (2048x1024) -> WqT (1024x2048)
//   blocks [2048,4096)   : transpose+cast Wk             -> WkT
//   blocks [4096,36864)  : cast Q|K fp32 -> fp16 into contiguous Qh|Kh
// All parts independent; merging removes 1 launch + tails vs round 5.
// ---------------------------------------------------------------------------
__global__ __launch_bounds__(256) void prep_kernel(
    const float* __restrict__ Wq, _Float16* __restrict__ WqT,
    const float* __restrict__ Wk, _Float16* __restrict__ WkT,
    const float* __restrict__ Q,  const float* __restrict__ K_,
    _Float16* __restrict__ QKh) {
  const int b = blockIdx.x;
  if (b < 4096) {
    const float* __restrict__ W  = (b < 2048) ? Wq : Wk;
    _Float16*    __restrict__ Wt = (b < 2048) ? WqT : WkT;
    const int bb = b & 2047;
    const int bx = bb & 31;        // C/32 = 1024/32 = 32
    const int by = bb >> 5;        // R/32 = 2048/32 = 64
    __shared__ float tile[32][33];
    const int tx = threadIdx.x & 31, ty = threadIdx.x >> 5;
    const int c = bx * 32 + tx, r0 = by * 32;
    for (int i = ty; i < 32; i += 8)
      tile[i][tx] = W[(size_t)(r0 + i) * 1024 + c];
    __syncthreads();
    const int out_c = r0 + tx, oc0 = bx * 32;
    for (int i = ty; i < 32; i += 8)
      Wt[(size_t)(oc0 + i) * 2048 + out_c] = (_Float16)tile[tx][i];
  } else {
    const int half4 = 8192 * 2048 / 4;             // 4194304
    const int i = (b - 4096) * 256 + (int)threadIdx.x;  // [0, 2*half4)
    const float4 v = (i < half4) ? ((const float4*)Q)[i]
                                 : ((const float4*)K_)[i - half4];
    f16x4 h;
    h[0] = (_Float16)v.x; h[1] = (_Float16)v.y;
    h[2] = (_Float16)v.z; h[3] = (_Float16)v.w;
    ((f16x4*)QKh)[i] = h;
  }
}

// ---------------------------------------------------------------------------
// MID (one launch), runs between the two GEMMs:
//   blocks [0,2048)      : scale[row] = Qf.Kf / (sum Qf * sum Kf + eps),
//                          one WAVE per row (4 rows/block), no LDS reduce.
//   blocks [2048,6144)   : transpose+cast Wv (2048x2048) -> WvT (over WqT)
//   blocks [6144,22528)  : cast V -> Vh  (ONLY when launched with full grid;
//                          requires Vh NOT to alias QfH/KfH, i.e. ws >= 73MB,
//                          since same-launch ordering vs the reduce blocks is
//                          undefined)
// ---------------------------------------------------------------------------
__global__ __launch_bounds__(256) void mid_kernel(
    const _Float16* __restrict__ QfH, const _Float16* __restrict__ KfH,
    float* __restrict__ scale,
    const float* __restrict__ Wv, _Float16* __restrict__ WvT,
    const float* __restrict__ V, _Float16* __restrict__ Vh) {
  const int b = blockIdx.x;
  if (b < 2048) {
    const int wv = threadIdx.x >> 6, lane = threadIdx.x & 63;
    const int row = b * 4 + wv;
    const _Float16* qrow = QfH + (size_t)row * 1024;
    const _Float16* krow = KfH + (size_t)row * 1024;
    const f16x8 q0 = ((const f16x8*)qrow)[lane * 2];
    const f16x8 q1 = ((const f16x8*)qrow)[lane * 2 + 1];
    const f16x8 k0 = ((const f16x8*)krow)[lane * 2];
    const f16x8 k1 = ((const f16x8*)krow)[lane * 2 + 1];
    float qk = 0.f, sq = 0.f, sk = 0.f;
#pragma unroll
    for (int i = 0; i < 8; ++i) {
      float q = (float)q0[i], k = (float)k0[i];
      qk += q * k; sq += q; sk += k;
      q = (float)q1[i]; k = (float)k1[i];
      qk += q * k; sq += q; sk += k;
    }
#pragma unroll
    for (int off = 32; off > 0; off >>= 1) {
      qk += __shfl_down(qk, off, 64);
      sq += __shfl_down(sq, off, 64);
      sk += __shfl_down(sk, off, 64);
    }
    if (lane == 0) scale[row] = qk / (sq * sk + 1e-6f);
  } else if (b < 6144) {
    const int bb = b - 2048;
    const int bx = bb & 63;        // 2048/32 = 64
    const int by = bb >> 6;
    __shared__ float tile[32][33];
    const int tx = threadIdx.x & 31, ty = threadIdx.x >> 5;
    const int c = bx * 32 + tx, r0 = by * 32;
    for (int i = ty; i < 32; i += 8)
      tile[i][tx] = Wv[(size_t)(r0 + i) * 2048 + c];
    __syncthreads();
    const int out_c = r0 + tx, oc0 = bx * 32;
    for (int i = ty; i < 32; i += 8)
      WvT[(size_t)(oc0 + i) * 2048 + out_c] = (_Float16)tile[tx][i];
  } else {
    const int i = (b - 6144) * 256 + (int)threadIdx.x;  // [0, 4194304)
    const float4 v = ((const float4*)V)[i];
    f16x4 h;
    h[0] = (_Float16)v.x; h[1] = (_Float16)v.y;
    h[2] = (_Float16)v.z; h[3] = (_Float16)v.w;
    ((f16x4*)Vh)[i] = h;
  }
}

// ---------------------------------------------------------------------------
// 256x256 deep-pipelined GEMM, 8 waves, BK=32, 3-tile prefetch ring,
// two-phase window (round-5 schedule, UNCHANGED in round 6 -- measured
// 73.5us / MfmaUtil 39.5% / FETCH 49.6MB / 0 bank conflicts).
//   C(MxN) = A(MxK fp16) @ Bt(NxK fp16)^T + bias
//   MODE 0: C = elu(acc + bias)           MODE 1: C = scale[row]*(acc + bias)
// ---------------------------------------------------------------------------
#define STG8(kk, h, slotv) do {                                                \
    __builtin_amdgcn_global_load_lds(GPTR(aRow + (h) * hstep + (kk)),          \
        SPTR(Aring + (slotv) * 4096 + wave * 512), 16, 0, 0);                  \
    __builtin_amdgcn_global_load_lds(GPTR(bRow + (h) * hstep + (kk)),          \
        SPTR(Bring + (slotv) * 4096 + wave * 512), 16, 0, 0);                  \
  } while (0)

#define WINDOW8(t_, DOSTG, DOWAIT, VCSTR) do {                                 \
    const int e_ = (2 * (t_)) & 7;                                             \
    const _Float16* Ab_ = Aring + ((e_ + wm) & 7) * 4096;                      \
    const _Float16* Bb_ = Bring + ((e_ + (wn >> 1)) & 7) * 4096                \
                          + (wn & 1) * 2048;                                   \
    f16x8 bf_[4], afL_[4], afH_[4];                                            \
    /* ---- phase A: reads first, then stage, then barrier ---- */             \
    _Pragma("unroll")                                                          \
    for (int j_ = 0; j_ < 4; ++j_)                                             \
      bf_[j_] = *(const f16x8*)(Bb_ + j_ * 512 + lane_c * 8);                  \
    _Pragma("unroll")                                                          \
    for (int i_ = 0; i_ < 4; ++i_)                                             \
      afL_[i_] = *(const f16x8*)(Ab_ + i_ * 512 + lane_c * 8);                 \
    if (DOSTG) STG8(((t_) + 3) * 32, 0, (e_ + 6) & 7);                         \
    __builtin_amdgcn_s_barrier();                                              \
    asm volatile("" ::: "memory");                                             \
    __builtin_amdgcn_s_setprio(1);                                             \
    _Pragma("unroll")                                                          \
    for (int i_ = 0; i_ < 4; ++i_)                                             \
      _Pragma("unroll")                                                        \
      for (int j_ = 0; j_ < 4; ++j_)                                           \
        acc[i_][j_] = __builtin_amdgcn_mfma_f32_16x16x32_f16(afL_[i_], bf_[j_],\
                                                             acc[i_][j_],      \
                                                             0, 0, 0);         \
    __builtin_amdgcn_s_setprio(0);                                             \
    /* ---- phase B: reads first, then stage, vmcnt, barrier ---- */           \
    _Pragma("unroll")                                                          \
    for (int i_ = 0; i_ < 4; ++i_)                                             \
      afH_[i_] = *(const f16x8*)(Ab_ + (i_ + 4) * 512 + lane_c * 8);           \
    if (DOSTG) STG8(((t_) + 3) * 32, 1, (e_ + 7) & 7);                         \
    if (DOWAIT) asm volatile("s_waitcnt vmcnt(" VCSTR ")" ::: "memory");       \
    __builtin_amdgcn_s_barrier();                                              \
    asm volatile("" ::: "memory");                                             \
    __builtin_amdgcn_s_setprio(1);                                             \
    _Pragma("unroll")                                                          \
    for (int i_ = 0; i_ < 4; ++i_)                                             \
      _Pragma("unroll")                                                        \
      for (int j_ = 0; j_ < 4; ++j_)                                           \
        acc[i_ + 4][j_] = __builtin_amdgcn_mfma_f32_16x16x32_f16(afH_[i_],     \
                                                                 bf_[j_],      \
                                                                 acc[i_ + 4][j_],\
                                                                 0, 0, 0);     \
    __builtin_amdgcn_s_setprio(0);                                             \
  } while (0)

template <int MODE, bool OUTHALF>
__global__ __launch_bounds__(512, 2) void gemm8p(
    const _Float16* __restrict__ A,
    const _Float16* __restrict__ Bt0, const _Float16* __restrict__ Bt1,
    const float* __restrict__ bias0, const float* __restrict__ bias1,
    int msplit, const float* __restrict__ scale,
    void* __restrict__ Cv, int K, int N) {
  // 8 half-tile slots per operand, 8 KiB (4096 halves) each: 128 KiB total.
  __shared__ __align__(16) _Float16 Aring[8 * 4096];
  __shared__ __align__(16) _Float16 Bring[8 * 4096];

  const int tid  = threadIdx.x;
  const int lane = tid & 63;
  const int wave = tid >> 6;       // 0..7
  const int quad = lane >> 4;
  const int r    = lane & 15;
  const int wm   = wave >> 2;      // 0..1  (M half)
  const int wn   = wave & 3;       // 0..3  (N quarter)

  // Bijective XCD-aware block swizzle (both grids: 256 blocks, %8 == 0).
  const int gx  = gridDim.x;
  const int nwg = gx * gridDim.y;
  int flat = blockIdx.y * gx + blockIdx.x;
  if ((nwg & 7) == 0) flat = (flat & 7) * (nwg >> 3) + (flat >> 3);
  const int m0 = (flat / gx) * 256;
  const int n0 = (flat % gx) * 256;

  const _Float16* Bt   = (m0 >= msplit) ? Bt1 : Bt0;
  const float*    bias = (m0 >= msplit) ? bias1 : bias0;

  // Per-thread staging source (pair-swizzle): 16B slot s = tid.
  const int sp  = tid >> 3;
  const int sub = (tid & 7) ^ (sp & 7);
  const int lr  = sp * 2 + (sub >> 2);   // local row in the 128-row half
  const int sc  = sub & 3;               // k-chunk (8 halves)
  const _Float16* aRow = A  + (size_t)(m0 + lr) * K + sc * 8;
  const _Float16* bRow = Bt + (size_t)(n0 + lr) * K + sc * 8;
  const int hstep = 128 * K;             // elements: half 0 -> half 1

  // Per-lane read constant: frag (lr=i*16+r, c=quad) lives at 16B slot
  // i*64 + lane_c, lane_c = (r>>1)*8 + ((((r&1)<<2)|quad) ^ (r>>1)).
  const int lane_c = (r >> 1) * 8 + (((((r & 1) << 2) | quad)) ^ (r >> 1));

  f32x4 acc[8][4] = {};
  const int NT = K >> 5;   // K/32 = 64 here (>= 4 required)

  // Prologue: stage tiles 0,1,2 (12 loads/thread, in order).
#pragma unroll
  for (int tt = 0; tt < 3; ++tt) {
    STG8(tt * 32, 0, (2 * tt) & 7);
    STG8(tt * 32, 1, (2 * tt + 1) & 7);
  }
  asm volatile("s_waitcnt vmcnt(8)" ::: "memory");   // tile 0 landed
  __builtin_amdgcn_s_barrier();
  asm volatile("" ::: "memory");

  for (int t = 0; t < NT - 3; ++t) WINDOW8(t, 1, 1, "8");
  WINDOW8(NT - 3, 0, 1, "4");
  WINDOW8(NT - 2, 0, 1, "0");
  WINDOW8(NT - 1, 0, 0, "0");

  // Epilogue: C/D layout col = lane&15, row = quad*4 + reg.
  float*    Cf = (float*)Cv;
  _Float16* Ch = (_Float16*)Cv;
#pragma unroll
  for (int i = 0; i < 8; ++i) {
    const int row0 = m0 + wm * 128 + i * 16 + quad * 4;
#pragma unroll
    for (int j = 0; j < 4; ++j) {
      const int col = n0 + wn * 64 + j * 16 + r;
      const float b = bias[col];
#pragma unroll
      for (int reg = 0; reg < 4; ++reg) {
        const int row = row0 + reg;
        float v = acc[i][j][reg] + b;
        if (MODE == 0) v = v > 0.f ? v : (expf(v) - 1.f);  // ELU (no +1)
        else           v = v * scale[row];
        if (OUTHALF) Ch[(size_t)row * N + col] = (_Float16)v;
        else         Cf[(size_t)row * N + col] = v;
      }
    }
  }
}

#undef STG8
#undef WINDOW8

// ---------------------------------------------------------------------------
// Legacy 128x128 GEMM kept for the small-workspace fallback path.
// ---------------------------------------------------------------------------
template <int MODE, bool AHALF, bool OUTHALF>
__global__ __launch_bounds__(256) void gemm2(
    const void* __restrict__ Av,
    const _Float16* __restrict__ Bt0, const _Float16* __restrict__ Bt1,
    const float* __restrict__ bias0, const float* __restrict__ bias1,
    int msplit, const float* __restrict__ scale,
    void* __restrict__ Cv, int K, int N) {
  constexpr int BK = 64;
  __shared__ __align__(16) _Float16 As[128 * BK];
  __shared__ __align__(16) _Float16 Bs[128 * BK];

  const int tid  = threadIdx.x;
  const int lane = tid & 63;
  const int wave = tid >> 6;
  const int quad = lane >> 4;
  const int r    = lane & 15;
  const int wm   = wave >> 1;
  const int wn   = wave & 1;
  const int m0   = blockIdx.y * 128;
  const int n0   = blockIdx.x * 128;

  const _Float16* Bt  = (m0 >= msplit) ? Bt1 : Bt0;
  const float* bias   = (m0 >= msplit) ? bias1 : bias0;

  size_t aoff[4], boff[4];
  int slot[4];
#pragma unroll
  for (int t = 0; t < 4; ++t) {
    const int s  = wave * 256 + t * 64 + lane;
    const int n  = s >> 3;
    const int kc = (s & 7) ^ (n & 7);
    aoff[t] = (size_t)(m0 + n) * K + kc * 8;
    boff[t] = (size_t)(n0 + n) * K + kc * 8;
    slot[t] = s;
  }

  f32x4 acc[4][4] = {};
  const _Float16* Ah = (const _Float16*)Av;
  const float*    Af = (const float*)Av;

  for (int k0 = 0; k0 < K; k0 += BK) {
    __syncthreads();
    if (AHALF) {
#pragma unroll
      for (int t = 0; t < 4; ++t)
        __builtin_amdgcn_global_load_lds(GPTR(Ah + aoff[t] + k0),
                                         SPTR(As + (wave * 256 + t * 64) * 8),
                                         16, 0, 0);
    } else {
#pragma unroll
      for (int t = 0; t < 4; ++t) {
        const float* ap = Af + aoff[t] + k0;
        const float4 v0 = *(const float4*)ap;
        const float4 v1 = *(const float4*)(ap + 4);
        f16x8 h;
        h[0] = (_Float16)v0.x; h[1] = (_Float16)v0.y;
        h[2] = (_Float16)v0.z; h[3] = (_Float16)v0.w;
        h[4] = (_Float16)v1.x; h[5] = (_Float16)v1.y;
        h[6] = (_Float16)v1.z; h[7] = (_Float16)v1.w;
        *(f16x8*)(As + (size_t)slot[t] * 8) = h;
      }
    }
#pragma unroll
    for (int t = 0; t < 4; ++t)
      __builtin_amdgcn_global_load_lds(GPTR(Bt + boff[t] + k0),
                                       SPTR(Bs + (wave * 256 + t * 64) * 8),
                                       16, 0, 0);
    __syncthreads();

#pragma unroll
    for (int ki = 0; ki < 2; ++ki) {
      f16x8 af[4], bf[4];
#pragma unroll
      for (int i = 0; i < 4; ++i) {
        const int an = wm * 64 + i * 16 + r;
        af[i] = *(const f16x8*)(As + (an * 8 + ((ki * 4 + quad) ^ (an & 7))) * 8);
      }
#pragma unroll
      for (int j = 0; j < 4; ++j) {
        const int bn = wn * 64 + j * 16 + r;
        bf[j] = *(const f16x8*)(Bs + (bn * 8 + ((ki * 4 + quad) ^ (bn & 7))) * 8);
      }
#pragma unroll
      for (int i = 0; i < 4; ++i)
#pragma unroll
        for (int j = 0; j < 4; ++j)
          acc[i][j] = __builtin_amdgcn_mfma_f32_16x16x32_f16(af[i], bf[j],
                                                             acc[i][j], 0, 0, 0);
    }
  }

  float*    Cf = (float*)Cv;
  _Float16* Ch = (_Float16*)Cv;
#pragma unroll
  for (int i = 0; i < 4; ++i) {
#pragma unroll
    for (int j = 0; j < 4; ++j) {
      const int col = n0 + wn * 64 + j * 16 + r;
      const float b = bias[col];
#pragma unroll
      for (int reg = 0; reg < 4; ++reg) {
        const int row = m0 + wm * 64 + i * 16 + quad * 4 + reg;
        float v = acc[i][j][reg] + b;
        if (MODE == 0) v = v > 0.f ? v : (expf(v) - 1.f);
        else           v = v * scale[row];
        if (OUTHALF) Ch[(size_t)row * N + col] = (_Float16)v;
        else         Cf[(size_t)row * N + col] = v;
      }
    }
  }
}

// ---------------------------------------------------------------------------
// scale[b] = (Qf[b].Kf[b]) / (sum(Qf[b]) * sum(Kf[b]) + eps), F = 1024.
// (fallback path only)
// ---------------------------------------------------------------------------
template <bool HALF>
__global__ void reduce_scale2(const void* __restrict__ Qf,
                              const void* __restrict__ Kf,
                              float* __restrict__ scale) {
  const int b = blockIdx.x;
  const int t = threadIdx.x;
  float q[4], k[4];
  if (HALF) {
    const f16x4 qh = ((const f16x4*)((const _Float16*)Qf + (size_t)b * 1024))[t];
    const f16x4 kh = ((const f16x4*)((const _Float16*)Kf + (size_t)b * 1024))[t];
#pragma unroll
    for (int i = 0; i < 4; ++i) { q[i] = (float)qh[i]; k[i] = (float)kh[i]; }
  } else {
    const float4 qv = ((const float4*)((const float*)Qf + (size_t)b * 1024))[t];
    const float4 kv = ((const float4*)((const float*)Kf + (size_t)b * 1024))[t];
    q[0] = qv.x; q[1] = qv.y; q[2] = qv.z; q[3] = qv.w;
    k[0] = kv.x; k[1] = kv.y; k[2] = kv.z; k[3] = kv.w;
  }
  float qk = q[0] * k[0] + q[1] * k[1] + q[2] * k[2] + q[3] * k[3];
  float sq = q[0] + q[1] + q[2] + q[3];
  float sk = k[0] + k[1] + k[2] + k[3];
#pragma unroll
  for (int off = 32; off > 0; off >>= 1) {
    qk += __shfl_down(qk, off, 64);
    sq += __shfl_down(sq, off, 64);
    sk += __shfl_down(sk, off, 64);
  }
  __shared__ float buf[3][4];
  const int lane = t & 63, wv = t >> 6;
  if (lane == 0) { buf[0][wv] = qk; buf[1][wv] = sq; buf[2][wv] = sk; }
  __syncthreads();
  if (t == 0) {
    const float QK = buf[0][0] + buf[0][1] + buf[0][2] + buf[0][3];
    const float SQ = buf[1][0] + buf[1][1] + buf[1][2] + buf[1][3];
    const float SK = buf[2][0] + buf[2][1] + buf[2][2] + buf[2][3];
    scale[b] = QK / (SQ * SK + 1e-6f);
  }
}

// ---------------------------------------------------------------------------
extern "C" void kernel_launch(void* const* d_in, const int* in_sizes, int n_in,
                              void* d_out, int out_size, void* d_ws,
                              size_t ws_size, hipStream_t stream) {
  const float* Q  = (const float*)d_in[0];
  const float* K_ = (const float*)d_in[1];
  const float* V  = (const float*)d_in[2];
  const float* Wq = (const float*)d_in[3];
  const float* bq = (const float*)d_in[4];
  const float* Wk = (const float*)d_in[5];
  const float* bk = (const float*)d_in[6];
  const float* Wv = (const float*)d_in[7];
  const float* bv = (const float*)d_in[8];
  float* out = (float*)d_out;

  const int B = 8192, D = 2048, F = 1024;
  const size_t MiB = 1u << 20;
  char* ws = (char*)d_ws;

  // Fast path ws layout:
  //   [0, 8M):      WqT(4M)+WkT(4M); WvT(8M) overwrites after feat GEMM
  //   [8M, 40M):    QfH(16M)+KfH(16M) contiguous
  //   [40M, +32K):  scale
  //   [41M, 73M):   Vh  (ONLY if ws >= 73M; else Vh reuses [8M,24M) via a
  //                 separate cast launch AFTER mid_kernel's reduce)
  const size_t NEED_FAST  = 40 * MiB + 64 * 1024;
  const size_t NEED_FAST2 = 73 * MiB;

  if (ws_size >= NEED_FAST) {
    _Float16* WqT = (_Float16*)ws;
    _Float16* WkT = (_Float16*)(ws + 4 * MiB);
    _Float16* WvT = (_Float16*)ws;             // reuses weight region
    _Float16* QfH = (_Float16*)(ws + 8 * MiB);
    _Float16* KfH = (_Float16*)(ws + 24 * MiB);
    float* scale  = (float*)(ws + 40 * MiB);
    const bool merged = (ws_size >= NEED_FAST2);
    _Float16* Vh = merged ? (_Float16*)(ws + 41 * MiB)
                          : (_Float16*)(ws + 8 * MiB);  // over QfH (post-reduce)
    _Float16* Qh = (_Float16*)d_out;                  // d_out as fp16 scratch
    _Float16* Kh = (_Float16*)d_out + (size_t)B * D;  // adjacent -> stacked M
    (void)Kh;

    // 1) prep: WqT + WkT transpose, Q|K cast   (2048+2048+32768 blocks)
    prep_kernel<<<36864, 256, 0, stream>>>(Wq, WqT, Wk, WkT, Q, K_, Qh);

    // 2) stacked feature GEMM: M = 16384 ([Qh;Kh]), msplit 8192 selects
    //    Wq/bq vs Wk/bk. Grid 4x64 = 256 blocks, 512 thr, 128 KiB LDS.
    gemm8p<0, true><<<dim3(F / 256, (2 * B) / 256), 512, 0, stream>>>(
        Qh, WqT, WkT, bq, bk, B, nullptr, QfH, D, F);

    // 3) mid: reduce(scale) + WvT transpose (+ V cast when merged).
    if (merged) {
      mid_kernel<<<22528, 256, 0, stream>>>(QfH, KfH, scale, Wv, WvT, V, Vh);
    } else {
      mid_kernel<<<6144, 256, 0, stream>>>(QfH, KfH, scale, Wv, WvT, V, Vh);
      cast_f32_f16_kernel<<<(B * D / 4) / 256, 256, 0, stream>>>(V, Vh);
    }

    // 4) V-projection GEMM with fused scale.
    gemm8p<1, false><<<dim3(D / 256, B / 256), 512, 0, stream>>>(
        Vh, WvT, WvT, bv, bv, 1 << 30, scale, out, D, D);
  } else {
    // Fallback: fp32 A staging in-kernel, Qf/Kf fp32 in d_out.
    _Float16* WqT = (_Float16*)ws;
    _Float16* WkT = (_Float16*)(ws + 4 * MiB);
    _Float16* WvT = (_Float16*)(ws + 8 * MiB);
    float* scale  = (float*)(ws + 16 * MiB);
    float* Qf = out;
    float* Kf = out + (size_t)B * F;

    dim3 tb(32, 8);
    transpose_cast_kernel<<<dim3(F / 32, D / 32), tb, 0, stream>>>(Wq, WqT, D, F);
    transpose_cast_kernel<<<dim3(F / 32, D / 32), tb, 0, stream>>>(Wk, WkT, D, F);
    transpose_cast_kernel<<<dim3(D / 32, D / 32), tb, 0, stream>>>(Wv, WvT, D, D);

    gemm2<0, false, false><<<dim3(F / 128, B / 128), 256, 0, stream>>>(
        Q, WqT, WqT, bq, bq, 1 << 30, nullptr, Qf, D, F);
    gemm2<0, false, false><<<dim3(F / 128, B / 128), 256, 0, stream>>>(
        K_, WkT, WkT, bk, bk, 1 << 30, nullptr, Kf, D, F);
    reduce_scale2<false><<<B, 256, 0, stream>>>(Qf, Kf, scale);
    gemm2<1, false, false><<<dim3(D / 128, B / 128), 256, 0, stream>>>(
        V, WvT, WvT, bv, bv, 1 << 30, scale, out, D, D);
  }
}